// Round 1
// baseline (5386.683 us; speedup 1.0000x reference)
//
#include <hip/hip_runtime.h>
#include <math.h>

#define S_LEN 2048
#define HIDDEN 4096
#define NUM_HEADS 32
#define NUM_KV_HEADS 8
#define HEAD_DIM 128
#define NEG (-1e9f)

// ---------------------------------------------------------------------------
// Generic tiled fp32 GEMM: C[M,N] = A[M,K] @ B[K,N]
// 64x64 tile, K-step 16, 256 threads, 4x4 accum per thread.
// M,N,K all divisible by tile dims in this problem (2048/4096/1024).
// ---------------------------------------------------------------------------
#define TM 64
#define TN 64
#define TK 16

__global__ __launch_bounds__(256) void gemm_f32(const float* __restrict__ A,
                                                const float* __restrict__ B,
                                                float* __restrict__ C,
                                                int M, int N, int K) {
  __shared__ float As[TK][TM + 1];
  __shared__ float Bs[TK][TN + 1];
  const int t = threadIdx.x;
  const int bm = blockIdx.y * TM;
  const int bn = blockIdx.x * TN;
  const int tx = t & 15, ty = t >> 4;

  float acc[4][4] = {};

  for (int k0 = 0; k0 < K; k0 += TK) {
    // A tile: 64 rows x 16 cols -> 256 float4 loads, 1 per thread
    {
      const int row = t >> 2;
      const int c4 = (t & 3) << 2;
      const float4 a4 = *reinterpret_cast<const float4*>(
          &A[(size_t)(bm + row) * K + k0 + c4]);
      As[c4 + 0][row] = a4.x;
      As[c4 + 1][row] = a4.y;
      As[c4 + 2][row] = a4.z;
      As[c4 + 3][row] = a4.w;
    }
    // B tile: 16 rows x 64 cols -> 256 float4 loads, 1 per thread
    {
      const int row = t >> 4;
      const int c4 = (t & 15) << 2;
      const float4 b4 = *reinterpret_cast<const float4*>(
          &B[(size_t)(k0 + row) * N + bn + c4]);
      Bs[row][c4 + 0] = b4.x;
      Bs[row][c4 + 1] = b4.y;
      Bs[row][c4 + 2] = b4.z;
      Bs[row][c4 + 3] = b4.w;
    }
    __syncthreads();
#pragma unroll
    for (int kk = 0; kk < TK; ++kk) {
      float a[4], b[4];
#pragma unroll
      for (int i = 0; i < 4; ++i) a[i] = As[kk][ty * 4 + i];
#pragma unroll
      for (int j = 0; j < 4; ++j) b[j] = Bs[kk][tx * 4 + j];
#pragma unroll
      for (int i = 0; i < 4; ++i)
#pragma unroll
        for (int j = 0; j < 4; ++j) acc[i][j] += a[i] * b[j];
    }
    __syncthreads();
  }

#pragma unroll
  for (int i = 0; i < 4; ++i) {
    const int row = bm + ty * 4 + i;
#pragma unroll
    for (int j = 0; j < 4; ++j)
      C[(size_t)row * N + bn + tx * 4 + j] = acc[i][j];
  }
}

// ---------------------------------------------------------------------------
// RoPE applied in-place to q (32 heads) and k (8 heads).
// One thread per (s, head, d) with d < 64; heads 0..31 -> q, 32..39 -> k.
// ---------------------------------------------------------------------------
__global__ void rope_kernel(float* __restrict__ q, float* __restrict__ k,
                            const int* __restrict__ pos_ids) {
  const int idx = blockIdx.x * 256 + threadIdx.x;
  const int d = idx & 63;
  const int rest = idx >> 6;
  const int head = rest % (NUM_HEADS + NUM_KV_HEADS);
  const int s = rest / (NUM_HEADS + NUM_KV_HEADS);
  if (s >= S_LEN) return;

  const float pos = (float)pos_ids[s];
  const float inv = powf(10000.0f, -(float)d / 64.0f);
  const float ang = pos * inv;
  const float c = cosf(ang);
  const float sn = sinf(ang);

  float* base = (head < NUM_HEADS)
                    ? (q + (size_t)s * (NUM_HEADS * HEAD_DIM) + head * HEAD_DIM)
                    : (k + (size_t)s * (NUM_KV_HEADS * HEAD_DIM) +
                       (head - NUM_HEADS) * HEAD_DIM);
  const float x1 = base[d];
  const float x2 = base[d + 64];
  base[d] = x1 * c - x2 * sn;
  base[d + 64] = x2 * c + x1 * sn;
}

// ---------------------------------------------------------------------------
// Flash-style causal GQA attention, fp32.
// Grid: (S/64 q-blocks, 32 heads). 256 threads (4 waves).
// Per block: 64 q rows. K/V iterated in tiles of 32 rows.
// Thread layout (tx = t&15, ty = t>>4):
//   scores : rows ty*4+i (i<4), k cols tx*2+j (j<2)
//   PV/out : rows ty*4+i (i<4), d cols tx*8+j (j<8)
// Row statistics (max, sum) reduced over the 16 tx lanes via __shfl_xor w16.
// Causal mask: s += -1e9 when kg > qg (numerically identical to the
// reference's additive mask; expf underflows to exactly 0).
// ---------------------------------------------------------------------------
#define QB 64
#define KT 32

__global__ __launch_bounds__(256) void attn_kernel(
    const float* __restrict__ Q, const float* __restrict__ K,
    const float* __restrict__ V, float* __restrict__ O) {
  __shared__ float Qs[QB][HEAD_DIM];      // 32 KB (reads are broadcast)
  __shared__ float KVs[KT][HEAD_DIM + 1]; // 16.5 KB, shared by K then V
  __shared__ float Ps[QB][KT + 2];        // 8.5 KB

  const int qb = blockIdx.x;
  const int h = blockIdx.y;
  const int hk = h >> 2;  // GQA: groups of 4 q heads share one kv head
  const int t = threadIdx.x;
  const int tx = t & 15, ty = t >> 4;

  // load Q tile: 64 x 128 floats = 2048 float4, 8 per thread
#pragma unroll
  for (int r = 0; r < 8; ++r) {
    const int idx = r * 256 + t;
    const int row = idx >> 5;        // 32 float4 per row
    const int c4 = (idx & 31) << 2;
    *reinterpret_cast<float4*>(&Qs[row][c4]) =
        *reinterpret_cast<const float4*>(
            &Q[(size_t)(qb * QB + row) * (NUM_HEADS * HEAD_DIM) +
               h * HEAD_DIM + c4]);
  }

  float acc[4][8] = {};
  float mrow[4], lrow[4];
#pragma unroll
  for (int i = 0; i < 4; ++i) {
    mrow[i] = -3.0e38f;
    lrow[i] = 0.0f;
  }

  const float scale = 0.08838834764831845f;  // 128^-0.5
  const int ktiles = 2 * qb + 2;             // cover k <= qb*64+63

  for (int kt = 0; kt < ktiles; ++kt) {
    __syncthreads();
    // load K tile: 32 x 128 = 1024 float4, 4 per thread
#pragma unroll
    for (int r = 0; r < 4; ++r) {
      const int idx = r * 256 + t;
      const int row = idx >> 5;
      const int c4 = (idx & 31) << 2;
      const float4 v4 = *reinterpret_cast<const float4*>(
          &K[(size_t)(kt * KT + row) * (NUM_KV_HEADS * HEAD_DIM) +
             hk * HEAD_DIM + c4]);
      KVs[row][c4 + 0] = v4.x;
      KVs[row][c4 + 1] = v4.y;
      KVs[row][c4 + 2] = v4.z;
      KVs[row][c4 + 3] = v4.w;
    }
    __syncthreads();

    // scores
    float sc[4][2];
#pragma unroll
    for (int i = 0; i < 4; ++i)
#pragma unroll
      for (int j = 0; j < 2; ++j) sc[i][j] = 0.0f;
    for (int dd = 0; dd < HEAD_DIM; ++dd) {
      float a[4], b[2];
#pragma unroll
      for (int i = 0; i < 4; ++i) a[i] = Qs[ty * 4 + i][dd];
#pragma unroll
      for (int j = 0; j < 2; ++j) b[j] = KVs[tx * 2 + j][dd];
#pragma unroll
      for (int i = 0; i < 4; ++i)
#pragma unroll
        for (int j = 0; j < 2; ++j) sc[i][j] += a[i] * b[j];
    }

    const bool need_mask = (kt * KT + KT - 1) > (qb * QB);
#pragma unroll
    for (int i = 0; i < 4; ++i) {
      const int qg = qb * QB + ty * 4 + i;
#pragma unroll
      for (int j = 0; j < 2; ++j) {
        float v = sc[i][j] * scale;
        if (need_mask) {
          const int kg = kt * KT + tx * 2 + j;
          if (kg > qg) v += NEG;
        }
        sc[i][j] = v;
      }
    }

    // online softmax update per row
#pragma unroll
    for (int i = 0; i < 4; ++i) {
      float mx = fmaxf(sc[i][0], sc[i][1]);
#pragma unroll
      for (int off = 1; off < 16; off <<= 1)
        mx = fmaxf(mx, __shfl_xor(mx, off, 16));
      const float mnew = fmaxf(mrow[i], mx);
      const float p0 = __expf(sc[i][0] - mnew);
      const float p1 = __expf(sc[i][1] - mnew);
      float su = p0 + p1;
#pragma unroll
      for (int off = 1; off < 16; off <<= 1) su += __shfl_xor(su, off, 16);
      const float r = __expf(mrow[i] - mnew);
      lrow[i] = lrow[i] * r + su;
      mrow[i] = mnew;
#pragma unroll
      for (int j = 0; j < 8; ++j) acc[i][j] *= r;
      Ps[ty * 4 + i][tx * 2 + 0] = p0;
      Ps[ty * 4 + i][tx * 2 + 1] = p1;
    }
    __syncthreads();

    // load V tile into the same buffer
#pragma unroll
    for (int r = 0; r < 4; ++r) {
      const int idx = r * 256 + t;
      const int row = idx >> 5;
      const int c4 = (idx & 31) << 2;
      const float4 v4 = *reinterpret_cast<const float4*>(
          &V[(size_t)(kt * KT + row) * (NUM_KV_HEADS * HEAD_DIM) +
             hk * HEAD_DIM + c4]);
      KVs[row][c4 + 0] = v4.x;
      KVs[row][c4 + 1] = v4.y;
      KVs[row][c4 + 2] = v4.z;
      KVs[row][c4 + 3] = v4.w;
    }
    __syncthreads();

    // O += P @ V
    for (int kk = 0; kk < KT; ++kk) {
      float b[8];
#pragma unroll
      for (int j = 0; j < 8; ++j) b[j] = KVs[kk][tx * 8 + j];
#pragma unroll
      for (int i = 0; i < 4; ++i) {
        const float p = Ps[ty * 4 + i][kk];
#pragma unroll
        for (int j = 0; j < 8; ++j) acc[i][j] += p * b[j];
      }
    }
  }

  // normalize + write: out[s][h*128+d]
#pragma unroll
  for (int i = 0; i < 4; ++i) {
    const int row = qb * QB + ty * 4 + i;
    const float inv = 1.0f / lrow[i];
#pragma unroll
    for (int j = 0; j < 8; ++j)
      O[(size_t)row * (NUM_HEADS * HEAD_DIM) + h * HEAD_DIM + tx * 8 + j] =
          acc[i][j] * inv;
  }
}

// ---------------------------------------------------------------------------
// launch
// ---------------------------------------------------------------------------
extern "C" void kernel_launch(void* const* d_in, const int* in_sizes, int n_in,
                              void* d_out, int out_size, void* d_ws,
                              size_t ws_size, hipStream_t stream) {
  const float* hidden = (const float*)d_in[0];  // (1,2048,4096)
  // d_in[1] = attention_mask: pure causal, applied analytically
  const int* pos_ids = (const int*)d_in[2];     // (1,2048)
  const float* Wq = (const float*)d_in[3];      // (4096,4096)
  const float* Wk = (const float*)d_in[4];      // (4096,1024)
  const float* Wv = (const float*)d_in[5];      // (4096,1024)
  const float* Wo = (const float*)d_in[6];      // (4096,4096)
  float* out = (float*)d_out;                   // (1,2048,4096)

  // workspace layout (floats)
  float* q = (float*)d_ws;                         // 2048*4096
  float* k = q + (size_t)S_LEN * HIDDEN;           // 2048*1024
  float* v = k + (size_t)S_LEN * 1024;             // 2048*1024
  float* ao = v + (size_t)S_LEN * 1024;            // 2048*4096

  // Q/K/V projections
  gemm_f32<<<dim3(HIDDEN / TN, S_LEN / TM), 256, 0, stream>>>(
      hidden, Wq, q, S_LEN, HIDDEN, HIDDEN);
  gemm_f32<<<dim3(1024 / TN, S_LEN / TM), 256, 0, stream>>>(
      hidden, Wk, k, S_LEN, 1024, HIDDEN);
  gemm_f32<<<dim3(1024 / TN, S_LEN / TM), 256, 0, stream>>>(
      hidden, Wv, v, S_LEN, 1024, HIDDEN);

  // RoPE in-place on q and k
  {
    const int total = S_LEN * (NUM_HEADS + NUM_KV_HEADS) * 64;
    rope_kernel<<<(total + 255) / 256, 256, 0, stream>>>(q, k, pos_ids);
  }

  // attention -> ao[s][h*128+d]
  attn_kernel<<<dim3(S_LEN / QB, NUM_HEADS), 256, 0, stream>>>(q, k, v, ao);

  // output projection
  gemm_f32<<<dim3(HIDDEN / TN, S_LEN / TM), 256, 0, stream>>>(
      ao, Wo, out, S_LEN, HIDDEN, HIDDEN);
}

// Round 2
// 2073.838 us; speedup vs baseline: 2.5974x; 2.5974x over previous
//
#include <hip/hip_runtime.h>
#include <math.h>

#define S_LEN 2048
#define HIDDEN 4096
#define NUM_HEADS 32
#define NUM_KV_HEADS 8
#define HEAD_DIM 128
#define NEG (-1e9f)

using short8 = __attribute__((ext_vector_type(8))) short;
using f32x4 = __attribute__((ext_vector_type(4))) float;

// ---------------------------------------------------------------------------
// helpers
// ---------------------------------------------------------------------------
__device__ inline unsigned short f2bf(float f) {
  union { float f; unsigned u; } c;
  c.f = f;
  unsigned r = c.u + 0x7fffu + ((c.u >> 16) & 1u);  // RNE
  return (unsigned short)(r >> 16);
}
__device__ inline float bf2f(unsigned short h) {
  union { unsigned u; float f; } c;
  c.u = ((unsigned)h) << 16;
  return c.f;
}
__device__ inline void gload16(const void* g, void* l) {
  __builtin_amdgcn_global_load_lds(
      (const __attribute__((address_space(1))) unsigned*)g,
      (__attribute__((address_space(3))) unsigned*)l, 16, 0, 0);
}

// ---------------------------------------------------------------------------
// split fp32 -> (hi, lo) bf16, elementwise (row-major preserved)
// ---------------------------------------------------------------------------
__global__ __launch_bounds__(256) void split_mat(const float* __restrict__ X,
                                                 unsigned short* __restrict__ Xh,
                                                 unsigned short* __restrict__ Xl,
                                                 int n4) {
  const int i = blockIdx.x * 256 + threadIdx.x;
  if (i >= n4) return;
  const float4 x = *reinterpret_cast<const float4*>(&X[(size_t)i * 4]);
  ushort4 h, l;
  h.x = f2bf(x.x); l.x = f2bf(x.x - bf2f(h.x));
  h.y = f2bf(x.y); l.y = f2bf(x.y - bf2f(h.y));
  h.z = f2bf(x.z); l.z = f2bf(x.z - bf2f(h.z));
  h.w = f2bf(x.w); l.w = f2bf(x.w - bf2f(h.w));
  *reinterpret_cast<ushort4*>(&Xh[(size_t)i * 4]) = h;
  *reinterpret_cast<ushort4*>(&Xl[(size_t)i * 4]) = l;
}

// ---------------------------------------------------------------------------
// split + transpose: B[K][N] fp32 -> Th[N][K], Tl[N][K] bf16
// 32x32 tiles via LDS.
// ---------------------------------------------------------------------------
__global__ __launch_bounds__(256) void split_transpose(
    const float* __restrict__ B, unsigned short* __restrict__ Th,
    unsigned short* __restrict__ Tl, int K, int N) {
  __shared__ float ts[32][33];
  const int t = threadIdx.x;
  const int k0 = blockIdx.y * 32, n0 = blockIdx.x * 32;
  const int r = t >> 3, c4 = (t & 7) << 2;
  const float4 x = *reinterpret_cast<const float4*>(&B[(size_t)(k0 + r) * N + n0 + c4]);
  ts[r][c4 + 0] = x.x;
  ts[r][c4 + 1] = x.y;
  ts[r][c4 + 2] = x.z;
  ts[r][c4 + 3] = x.w;
  __syncthreads();
  const int col = r, ks = c4;
  ushort4 h, l;
#pragma unroll
  for (int e = 0; e < 4; ++e) {
    const float v = ts[ks + e][col];
    const unsigned short hh = f2bf(v);
    const unsigned short ll = f2bf(v - bf2f(hh));
    ((unsigned short*)&h)[e] = hh;
    ((unsigned short*)&l)[e] = ll;
  }
  *reinterpret_cast<ushort4*>(&Th[(size_t)(n0 + col) * K + k0 + ks]) = h;
  *reinterpret_cast<ushort4*>(&Tl[(size_t)(n0 + col) * K + k0 + ks]) = l;
}

// ---------------------------------------------------------------------------
// Split-bf16 MFMA GEMM: C[M][N] (fp32) = (Ah+Al)[M][K] @ (Bh+Bl)^T  where
// Bh/Bl are stored transposed as [N][K]. 128x128 tile, BK=32, 256 threads
// (4 waves, each computing a 64x64 quadrant as 4x4 16x16 fragments).
// 3 MFMA per fragment pair: hi*hi + hi*lo + lo*hi (fp32 accumulate).
// ---------------------------------------------------------------------------
#define BM 128
#define BN 128
#define BK 32

__global__ __launch_bounds__(256) void gemm_split(
    const unsigned short* __restrict__ Ah, const unsigned short* __restrict__ Al,
    const unsigned short* __restrict__ Bh, const unsigned short* __restrict__ Bl,
    float* __restrict__ C, int M, int N, int K) {
  __shared__ unsigned short sAh[BM * BK];
  __shared__ unsigned short sAl[BM * BK];
  __shared__ unsigned short sBh[BN * BK];
  __shared__ unsigned short sBl[BN * BK];

  const int t = threadIdx.x;
  const int lane = t & 63;
  const int w = t >> 6;
  const int bm = blockIdx.y * BM;
  const int bn = blockIdx.x * BN;
  const int wr = (w >> 1) * 64;  // wave row offset in tile
  const int wc = (w & 1) * 64;   // wave col offset in tile

  f32x4 acc[4][4] = {};

  const int lrow = lane & 15;
  const int kg = (lane >> 4) * 8;

  for (int k0 = 0; k0 < K; k0 += BK) {
    __syncthreads();
    // stage 4 buffers: each tile 128 rows x 32 k x 2B = 512 chunks of 16B
#pragma unroll
    for (int cc = 0; cc < 2; ++cc) {
      const int c = t + cc * 256;
      const int row = c >> 2, kk = (c & 3) * 8;
      const size_t ga = (size_t)(bm + row) * K + k0 + kk;
      const size_t gb = (size_t)(bn + row) * K + k0 + kk;
      gload16(Ah + ga, &sAh[c * 8]);
      gload16(Al + ga, &sAl[c * 8]);
      gload16(Bh + gb, &sBh[c * 8]);
      gload16(Bl + gb, &sBl[c * 8]);
    }
    __syncthreads();

    short8 ah[4], al[4], bh[4], bl[4];
#pragma unroll
    for (int i = 0; i < 4; ++i) {
      const int ar = (wr + i * 16 + lrow) * BK + kg;
      ah[i] = *reinterpret_cast<const short8*>(&sAh[ar]);
      al[i] = *reinterpret_cast<const short8*>(&sAl[ar]);
      const int br = (wc + i * 16 + lrow) * BK + kg;
      bh[i] = *reinterpret_cast<const short8*>(&sBh[br]);
      bl[i] = *reinterpret_cast<const short8*>(&sBl[br]);
    }
#pragma unroll
    for (int i = 0; i < 4; ++i)
#pragma unroll
      for (int j = 0; j < 4; ++j) {
        acc[i][j] = __builtin_amdgcn_mfma_f32_16x16x32_bf16(ah[i], bh[j], acc[i][j], 0, 0, 0);
        acc[i][j] = __builtin_amdgcn_mfma_f32_16x16x32_bf16(ah[i], bl[j], acc[i][j], 0, 0, 0);
        acc[i][j] = __builtin_amdgcn_mfma_f32_16x16x32_bf16(al[i], bh[j], acc[i][j], 0, 0, 0);
      }
  }

  // C/D layout (m89, verified): row = (lane>>4)*4 + reg, col = lane&15
#pragma unroll
  for (int i = 0; i < 4; ++i) {
    const int row0 = bm + wr + i * 16 + (lane >> 4) * 4;
#pragma unroll
    for (int j = 0; j < 4; ++j) {
      const int col = bn + wc + j * 16 + (lane & 15);
#pragma unroll
      for (int r = 0; r < 4; ++r)
        C[(size_t)(row0 + r) * N + col] = acc[i][j][r];
    }
  }
}

// ---------------------------------------------------------------------------
// fallback fp32 GEMM (used only if ws_size is too small for the split path)
// ---------------------------------------------------------------------------
#define TM 64
#define TN 64
#define TK 16

__global__ __launch_bounds__(256) void gemm_f32(const float* __restrict__ A,
                                                const float* __restrict__ B,
                                                float* __restrict__ C,
                                                int M, int N, int K) {
  __shared__ float As[TK][TM + 1];
  __shared__ float Bs[TK][TN + 1];
  const int t = threadIdx.x;
  const int bm = blockIdx.y * TM;
  const int bn = blockIdx.x * TN;
  const int tx = t & 15, ty = t >> 4;

  float acc[4][4] = {};

  for (int k0 = 0; k0 < K; k0 += TK) {
    {
      const int row = t >> 2;
      const int c4 = (t & 3) << 2;
      const float4 a4 = *reinterpret_cast<const float4*>(&A[(size_t)(bm + row) * K + k0 + c4]);
      As[c4 + 0][row] = a4.x;
      As[c4 + 1][row] = a4.y;
      As[c4 + 2][row] = a4.z;
      As[c4 + 3][row] = a4.w;
    }
    {
      const int row = t >> 4;
      const int c4 = (t & 15) << 2;
      const float4 b4 = *reinterpret_cast<const float4*>(&B[(size_t)(k0 + row) * N + bn + c4]);
      Bs[row][c4 + 0] = b4.x;
      Bs[row][c4 + 1] = b4.y;
      Bs[row][c4 + 2] = b4.z;
      Bs[row][c4 + 3] = b4.w;
    }
    __syncthreads();
#pragma unroll
    for (int kk = 0; kk < TK; ++kk) {
      float a[4], b[4];
#pragma unroll
      for (int i = 0; i < 4; ++i) a[i] = As[kk][ty * 4 + i];
#pragma unroll
      for (int j = 0; j < 4; ++j) b[j] = Bs[kk][tx * 4 + j];
#pragma unroll
      for (int i = 0; i < 4; ++i)
#pragma unroll
        for (int j = 0; j < 4; ++j) acc[i][j] += a[i] * b[j];
    }
    __syncthreads();
  }

#pragma unroll
  for (int i = 0; i < 4; ++i) {
    const int row = bm + ty * 4 + i;
#pragma unroll
    for (int j = 0; j < 4; ++j)
      C[(size_t)row * N + bn + tx * 4 + j] = acc[i][j];
  }
}

// ---------------------------------------------------------------------------
// RoPE in-place on q (32 heads) and k (8 heads)
// ---------------------------------------------------------------------------
__global__ void rope_kernel(float* __restrict__ q, float* __restrict__ k,
                            const int* __restrict__ pos_ids) {
  const int idx = blockIdx.x * 256 + threadIdx.x;
  const int d = idx & 63;
  const int rest = idx >> 6;
  const int head = rest % (NUM_HEADS + NUM_KV_HEADS);
  const int s = rest / (NUM_HEADS + NUM_KV_HEADS);
  if (s >= S_LEN) return;

  const float pos = (float)pos_ids[s];
  const float inv = powf(10000.0f, -(float)d / 64.0f);
  const float ang = pos * inv;
  const float c = cosf(ang);
  const float sn = sinf(ang);

  float* base = (head < NUM_HEADS)
                    ? (q + (size_t)s * (NUM_HEADS * HEAD_DIM) + head * HEAD_DIM)
                    : (k + (size_t)s * (NUM_KV_HEADS * HEAD_DIM) +
                       (head - NUM_HEADS) * HEAD_DIM);
  const float x1 = base[d];
  const float x2 = base[d + 64];
  base[d] = x1 * c - x2 * sn;
  base[d + 64] = x2 * c + x1 * sn;
}

// ---------------------------------------------------------------------------
// Flash-style causal GQA attention, fp32, bank-conflict-fixed:
//  - LDS row stride padded to 132 floats (528 B, 16B-aligned, odd multiple
//    of 4 dwords -> column reads spread across bank groups)
//  - score + PV inner loops vectorized to float4 (ds_read_b128)
// ---------------------------------------------------------------------------
#define QB 64
#define KT 32
#define PD 132

__global__ __launch_bounds__(256) void attn_kernel(
    const float* __restrict__ Q, const float* __restrict__ K,
    const float* __restrict__ V, float* __restrict__ O) {
  __shared__ float Qs[QB][PD];   // 33.8 KB
  __shared__ float KVs[KT][PD];  // 16.9 KB (K then V)
  __shared__ float Ps[QB][KT + 2];

  const int qb = blockIdx.x;
  const int h = blockIdx.y;
  const int hk = h >> 2;
  const int t = threadIdx.x;
  const int tx = t & 15, ty = t >> 4;

#pragma unroll
  for (int r = 0; r < 8; ++r) {
    const int idx = r * 256 + t;
    const int row = idx >> 5;
    const int c4 = (idx & 31) << 2;
    *reinterpret_cast<float4*>(&Qs[row][c4]) = *reinterpret_cast<const float4*>(
        &Q[(size_t)(qb * QB + row) * (NUM_HEADS * HEAD_DIM) + h * HEAD_DIM + c4]);
  }

  float acc[4][8] = {};
  float mrow[4], lrow[4];
#pragma unroll
  for (int i = 0; i < 4; ++i) {
    mrow[i] = -3.0e38f;
    lrow[i] = 0.0f;
  }

  const float scale = 0.08838834764831845f;
  const int ktiles = 2 * qb + 2;

  for (int kt = 0; kt < ktiles; ++kt) {
    __syncthreads();
#pragma unroll
    for (int r = 0; r < 4; ++r) {
      const int idx = r * 256 + t;
      const int row = idx >> 5;
      const int c4 = (idx & 31) << 2;
      *reinterpret_cast<float4*>(&KVs[row][c4]) = *reinterpret_cast<const float4*>(
          &K[(size_t)(kt * KT + row) * (NUM_KV_HEADS * HEAD_DIM) + hk * HEAD_DIM + c4]);
    }
    __syncthreads();

    float sc[4][2] = {};
    for (int d4 = 0; d4 < HEAD_DIM; d4 += 4) {
      float4 a[4], b[2];
#pragma unroll
      for (int i = 0; i < 4; ++i) a[i] = *reinterpret_cast<const float4*>(&Qs[ty * 4 + i][d4]);
#pragma unroll
      for (int j = 0; j < 2; ++j) b[j] = *reinterpret_cast<const float4*>(&KVs[tx * 2 + j][d4]);
#pragma unroll
      for (int i = 0; i < 4; ++i)
#pragma unroll
        for (int j = 0; j < 2; ++j)
          sc[i][j] += a[i].x * b[j].x + a[i].y * b[j].y + a[i].z * b[j].z + a[i].w * b[j].w;
    }

    const bool need_mask = (kt * KT + KT - 1) > (qb * QB);
#pragma unroll
    for (int i = 0; i < 4; ++i) {
      const int qg = qb * QB + ty * 4 + i;
#pragma unroll
      for (int j = 0; j < 2; ++j) {
        float v = sc[i][j] * scale;
        if (need_mask) {
          const int kg = kt * KT + tx * 2 + j;
          if (kg > qg) v += NEG;
        }
        sc[i][j] = v;
      }
    }

#pragma unroll
    for (int i = 0; i < 4; ++i) {
      float mx = fmaxf(sc[i][0], sc[i][1]);
#pragma unroll
      for (int off = 1; off < 16; off <<= 1) mx = fmaxf(mx, __shfl_xor(mx, off, 16));
      const float mnew = fmaxf(mrow[i], mx);
      const float p0 = __expf(sc[i][0] - mnew);
      const float p1 = __expf(sc[i][1] - mnew);
      float su = p0 + p1;
#pragma unroll
      for (int off = 1; off < 16; off <<= 1) su += __shfl_xor(su, off, 16);
      const float rsc = __expf(mrow[i] - mnew);
      lrow[i] = lrow[i] * rsc + su;
      mrow[i] = mnew;
#pragma unroll
      for (int j = 0; j < 8; ++j) acc[i][j] *= rsc;
      Ps[ty * 4 + i][tx * 2 + 0] = p0;
      Ps[ty * 4 + i][tx * 2 + 1] = p1;
    }
    __syncthreads();

#pragma unroll
    for (int r = 0; r < 4; ++r) {
      const int idx = r * 256 + t;
      const int row = idx >> 5;
      const int c4 = (idx & 31) << 2;
      *reinterpret_cast<float4*>(&KVs[row][c4]) = *reinterpret_cast<const float4*>(
          &V[(size_t)(kt * KT + row) * (NUM_KV_HEADS * HEAD_DIM) + hk * HEAD_DIM + c4]);
    }
    __syncthreads();

    for (int kk = 0; kk < KT; ++kk) {
      const float4 b0 = *reinterpret_cast<const float4*>(&KVs[kk][tx * 8]);
      const float4 b1 = *reinterpret_cast<const float4*>(&KVs[kk][tx * 8 + 4]);
#pragma unroll
      for (int i = 0; i < 4; ++i) {
        const float p = Ps[ty * 4 + i][kk];
        acc[i][0] += p * b0.x;
        acc[i][1] += p * b0.y;
        acc[i][2] += p * b0.z;
        acc[i][3] += p * b0.w;
        acc[i][4] += p * b1.x;
        acc[i][5] += p * b1.y;
        acc[i][6] += p * b1.z;
        acc[i][7] += p * b1.w;
      }
    }
  }

#pragma unroll
  for (int i = 0; i < 4; ++i) {
    const int row = qb * QB + ty * 4 + i;
    const float inv = 1.0f / lrow[i];
#pragma unroll
    for (int j = 0; j < 8; ++j)
      O[(size_t)row * (NUM_HEADS * HEAD_DIM) + h * HEAD_DIM + tx * 8 + j] = acc[i][j] * inv;
  }
}

// ---------------------------------------------------------------------------
// launch
// ---------------------------------------------------------------------------
extern "C" void kernel_launch(void* const* d_in, const int* in_sizes, int n_in,
                              void* d_out, int out_size, void* d_ws,
                              size_t ws_size, hipStream_t stream) {
  const float* hidden = (const float*)d_in[0];  // (1,2048,4096)
  const int* pos_ids = (const int*)d_in[2];     // (1,2048)
  const float* Wq = (const float*)d_in[3];      // (4096,4096)
  const float* Wk = (const float*)d_in[4];      // (4096,1024)
  const float* Wv = (const float*)d_in[5];      // (4096,1024)
  const float* Wo = (const float*)d_in[6];      // (4096,4096)
  float* out = (float*)d_out;                   // (1,2048,4096)

  char* ws = (char*)d_ws;
  const size_t SZ_Q = (size_t)S_LEN * HIDDEN * 4;   // 32 MB
  const size_t SZ_KV = (size_t)S_LEN * 1024 * 4;    // 8 MB
  const size_t SZ_AH = (size_t)S_LEN * HIDDEN * 2;  // 16 MB
  const size_t SZ_WH = (size_t)HIDDEN * HIDDEN * 2; // 32 MB

  float* q = (float*)(ws);
  float* k = (float*)(ws + SZ_Q);
  float* v = (float*)(ws + SZ_Q + SZ_KV);
  float* ao = (float*)(ws + SZ_Q + 2 * SZ_KV);
  unsigned short* Ah = (unsigned short*)(ws + 2 * SZ_Q + 2 * SZ_KV);
  unsigned short* Al = (unsigned short*)(ws + 2 * SZ_Q + 2 * SZ_KV + SZ_AH);
  unsigned short* Wh = (unsigned short*)(ws + 2 * SZ_Q + 2 * SZ_KV + 2 * SZ_AH);
  unsigned short* Wl = (unsigned short*)(ws + 2 * SZ_Q + 2 * SZ_KV + 2 * SZ_AH + SZ_WH);
  const size_t needed = 2 * SZ_Q + 2 * SZ_KV + 2 * SZ_AH + 2 * SZ_WH;  // 176 MB

  if (ws_size >= needed) {
    // ---- split-bf16 MFMA path ----
    const int n4_hidden = S_LEN * HIDDEN / 4;
    split_mat<<<(n4_hidden + 255) / 256, 256, 0, stream>>>(hidden, Ah, Al, n4_hidden);

    // Q projection
    split_transpose<<<dim3(HIDDEN / 32, HIDDEN / 32), 256, 0, stream>>>(Wq, Wh, Wl, HIDDEN, HIDDEN);
    gemm_split<<<dim3(HIDDEN / BN, S_LEN / BM), 256, 0, stream>>>(Ah, Al, Wh, Wl, q, S_LEN, HIDDEN, HIDDEN);
    // K projection
    split_transpose<<<dim3(1024 / 32, HIDDEN / 32), 256, 0, stream>>>(Wk, Wh, Wl, HIDDEN, 1024);
    gemm_split<<<dim3(1024 / BN, S_LEN / BM), 256, 0, stream>>>(Ah, Al, Wh, Wl, k, S_LEN, 1024, HIDDEN);
    // V projection
    split_transpose<<<dim3(1024 / 32, HIDDEN / 32), 256, 0, stream>>>(Wv, Wh, Wl, HIDDEN, 1024);
    gemm_split<<<dim3(1024 / BN, S_LEN / BM), 256, 0, stream>>>(Ah, Al, Wh, Wl, v, S_LEN, 1024, HIDDEN);

    {
      const int total = S_LEN * (NUM_HEADS + NUM_KV_HEADS) * 64;
      rope_kernel<<<(total + 255) / 256, 256, 0, stream>>>(q, k, pos_ids);
    }
    attn_kernel<<<dim3(S_LEN / QB, NUM_HEADS), 256, 0, stream>>>(q, k, v, ao);

    // output projection
    split_mat<<<(n4_hidden + 255) / 256, 256, 0, stream>>>(ao, Ah, Al, n4_hidden);
    split_transpose<<<dim3(HIDDEN / 32, HIDDEN / 32), 256, 0, stream>>>(Wo, Wh, Wl, HIDDEN, HIDDEN);
    gemm_split<<<dim3(HIDDEN / BN, S_LEN / BM), 256, 0, stream>>>(Ah, Al, Wh, Wl, out, S_LEN, HIDDEN, HIDDEN);
  } else {
    // ---- fallback fp32 path (80 MB ws) ----
    gemm_f32<<<dim3(HIDDEN / TN, S_LEN / TM), 256, 0, stream>>>(hidden, Wq, q, S_LEN, HIDDEN, HIDDEN);
    gemm_f32<<<dim3(1024 / TN, S_LEN / TM), 256, 0, stream>>>(hidden, Wk, k, S_LEN, 1024, HIDDEN);
    gemm_f32<<<dim3(1024 / TN, S_LEN / TM), 256, 0, stream>>>(hidden, Wv, v, S_LEN, 1024, HIDDEN);
    {
      const int total = S_LEN * (NUM_HEADS + NUM_KV_HEADS) * 64;
      rope_kernel<<<(total + 255) / 256, 256, 0, stream>>>(q, k, pos_ids);
    }
    attn_kernel<<<dim3(S_LEN / QB, NUM_HEADS), 256, 0, stream>>>(q, k, v, ao);
    gemm_f32<<<dim3(HIDDEN / TN, S_LEN / TM), 256, 0, stream>>>(ao, Wo, out, S_LEN, HIDDEN, HIDDEN);
  }
}

// Round 4
// 1241.022 us; speedup vs baseline: 4.3405x; 1.6711x over previous
//
#include <hip/hip_runtime.h>
#include <math.h>

#define S_LEN 2048
#define HIDDEN 4096
#define NUM_HEADS 32
#define NUM_KV_HEADS 8
#define HEAD_DIM 128
#define NEG (-1e9f)

using short8 = __attribute__((ext_vector_type(8))) short;
using f32x4 = __attribute__((ext_vector_type(4))) float;

// ---------------------------------------------------------------------------
// helpers
// ---------------------------------------------------------------------------
__device__ inline unsigned short f2bf(float f) {
  union { float f; unsigned u; } c;
  c.f = f;
  unsigned r = c.u + 0x7fffu + ((c.u >> 16) & 1u);  // RNE
  return (unsigned short)(r >> 16);
}
__device__ inline float bf2f(unsigned short h) {
  union { unsigned u; float f; } c;
  c.u = ((unsigned)h) << 16;
  return c.f;
}
__device__ inline void gload16(const void* g, void* l) {
  __builtin_amdgcn_global_load_lds(
      (const __attribute__((address_space(1))) unsigned*)g,
      (__attribute__((address_space(3))) unsigned*)l, 16, 0, 0);
}

// ---------------------------------------------------------------------------
// split fp32 -> (hi, lo) bf16, elementwise
// ---------------------------------------------------------------------------
__global__ __launch_bounds__(256) void split_mat(const float* __restrict__ X,
                                                 unsigned short* __restrict__ Xh,
                                                 unsigned short* __restrict__ Xl,
                                                 int n4) {
  const int i = blockIdx.x * 256 + threadIdx.x;
  if (i >= n4) return;
  const float4 x = *reinterpret_cast<const float4*>(&X[(size_t)i * 4]);
  ushort4 h, l;
  h.x = f2bf(x.x); l.x = f2bf(x.x - bf2f(h.x));
  h.y = f2bf(x.y); l.y = f2bf(x.y - bf2f(h.y));
  h.z = f2bf(x.z); l.z = f2bf(x.z - bf2f(h.z));
  h.w = f2bf(x.w); l.w = f2bf(x.w - bf2f(h.w));
  *reinterpret_cast<ushort4*>(&Xh[(size_t)i * 4]) = h;
  *reinterpret_cast<ushort4*>(&Xl[(size_t)i * 4]) = l;
}

// ---------------------------------------------------------------------------
// split + transpose: B[K][N] fp32 -> Th[N][K], Tl[N][K] bf16 (32x32 LDS tiles)
// ---------------------------------------------------------------------------
__global__ __launch_bounds__(256) void split_transpose(
    const float* __restrict__ B, unsigned short* __restrict__ Th,
    unsigned short* __restrict__ Tl, int K, int N) {
  __shared__ float ts[32][33];
  const int t = threadIdx.x;
  const int k0 = blockIdx.y * 32, n0 = blockIdx.x * 32;
  const int r = t >> 3, c4 = (t & 7) << 2;
  const float4 x = *reinterpret_cast<const float4*>(&B[(size_t)(k0 + r) * N + n0 + c4]);
  ts[r][c4 + 0] = x.x;
  ts[r][c4 + 1] = x.y;
  ts[r][c4 + 2] = x.z;
  ts[r][c4 + 3] = x.w;
  __syncthreads();
  const int col = r, ks = c4;
  ushort4 h, l;
#pragma unroll
  for (int e = 0; e < 4; ++e) {
    const float v = ts[ks + e][col];
    const unsigned short hh = f2bf(v);
    const unsigned short ll = f2bf(v - bf2f(hh));
    ((unsigned short*)&h)[e] = hh;
    ((unsigned short*)&l)[e] = ll;
  }
  *reinterpret_cast<ushort4*>(&Th[(size_t)(n0 + col) * K + k0 + ks]) = h;
  *reinterpret_cast<ushort4*>(&Tl[(size_t)(n0 + col) * K + k0 + ks]) = l;
}

// ---------------------------------------------------------------------------
// Split-bf16 MFMA GEMM (verified round 2): C = (Ah+Al) @ (Bh+Bl)^T
// ---------------------------------------------------------------------------
#define BM 128
#define BN 128
#define BK 32

__global__ __launch_bounds__(256) void gemm_split(
    const unsigned short* __restrict__ Ah, const unsigned short* __restrict__ Al,
    const unsigned short* __restrict__ Bh, const unsigned short* __restrict__ Bl,
    float* __restrict__ C, int M, int N, int K) {
  __shared__ unsigned short sAh[BM * BK];
  __shared__ unsigned short sAl[BM * BK];
  __shared__ unsigned short sBh[BN * BK];
  __shared__ unsigned short sBl[BN * BK];

  const int t = threadIdx.x;
  const int lane = t & 63;
  const int w = t >> 6;
  const int bm = blockIdx.y * BM;
  const int bn = blockIdx.x * BN;
  const int wr = (w >> 1) * 64;
  const int wc = (w & 1) * 64;

  f32x4 acc[4][4] = {};

  const int lrow = lane & 15;
  const int kg = (lane >> 4) * 8;

  for (int k0 = 0; k0 < K; k0 += BK) {
    __syncthreads();
#pragma unroll
    for (int cc = 0; cc < 2; ++cc) {
      const int c = t + cc * 256;
      const int row = c >> 2, kk = (c & 3) * 8;
      const size_t ga = (size_t)(bm + row) * K + k0 + kk;
      const size_t gb = (size_t)(bn + row) * K + k0 + kk;
      gload16(Ah + ga, &sAh[c * 8]);
      gload16(Al + ga, &sAl[c * 8]);
      gload16(Bh + gb, &sBh[c * 8]);
      gload16(Bl + gb, &sBl[c * 8]);
    }
    __syncthreads();

    short8 ah[4], al[4], bh[4], bl[4];
#pragma unroll
    for (int i = 0; i < 4; ++i) {
      const int ar = (wr + i * 16 + lrow) * BK + kg;
      ah[i] = *reinterpret_cast<const short8*>(&sAh[ar]);
      al[i] = *reinterpret_cast<const short8*>(&sAl[ar]);
      const int br = (wc + i * 16 + lrow) * BK + kg;
      bh[i] = *reinterpret_cast<const short8*>(&sBh[br]);
      bl[i] = *reinterpret_cast<const short8*>(&sBl[br]);
    }
#pragma unroll
    for (int i = 0; i < 4; ++i)
#pragma unroll
      for (int j = 0; j < 4; ++j) {
        acc[i][j] = __builtin_amdgcn_mfma_f32_16x16x32_bf16(ah[i], bh[j], acc[i][j], 0, 0, 0);
        acc[i][j] = __builtin_amdgcn_mfma_f32_16x16x32_bf16(ah[i], bl[j], acc[i][j], 0, 0, 0);
        acc[i][j] = __builtin_amdgcn_mfma_f32_16x16x32_bf16(al[i], bh[j], acc[i][j], 0, 0, 0);
      }
  }

#pragma unroll
  for (int i = 0; i < 4; ++i) {
    const int row0 = bm + wr + i * 16 + (lane >> 4) * 4;
#pragma unroll
    for (int j = 0; j < 4; ++j) {
      const int col = bn + wc + j * 16 + (lane & 15);
#pragma unroll
      for (int r = 0; r < 4; ++r)
        C[(size_t)(row0 + r) * N + col] = acc[i][j][r];
    }
  }
}

// ---------------------------------------------------------------------------
// RoPE + split-to-bf16(hi/lo): q fp32 -> Qh/Ql, k fp32 -> Kh/Kl
// ---------------------------------------------------------------------------
__global__ void rope_convert(const float* __restrict__ q, const float* __restrict__ k,
                             const int* __restrict__ pos_ids,
                             unsigned short* __restrict__ Qh, unsigned short* __restrict__ Ql,
                             unsigned short* __restrict__ Kh, unsigned short* __restrict__ Kl) {
  const int idx = blockIdx.x * 256 + threadIdx.x;
  const int d = idx & 63;
  const int rest = idx >> 6;
  const int head = rest % (NUM_HEADS + NUM_KV_HEADS);
  const int s = rest / (NUM_HEADS + NUM_KV_HEADS);
  if (s >= S_LEN) return;

  const float pos = (float)pos_ids[s];
  const float inv = powf(10000.0f, -(float)d / 64.0f);
  const float ang = pos * inv;
  const float c = cosf(ang);
  const float sn = sinf(ang);

  if (head < NUM_HEADS) {
    const size_t b = (size_t)s * (NUM_HEADS * HEAD_DIM) + head * HEAD_DIM;
    const float x1 = q[b + d], x2 = q[b + d + 64];
    const float y1 = x1 * c - x2 * sn;
    const float y2 = x2 * c + x1 * sn;
    const unsigned short h1 = f2bf(y1), h2 = f2bf(y2);
    Qh[b + d] = h1;       Ql[b + d] = f2bf(y1 - bf2f(h1));
    Qh[b + d + 64] = h2;  Ql[b + d + 64] = f2bf(y2 - bf2f(h2));
  } else {
    const size_t b = (size_t)s * (NUM_KV_HEADS * HEAD_DIM) + (head - NUM_HEADS) * HEAD_DIM;
    const float x1 = k[b + d], x2 = k[b + d + 64];
    const float y1 = x1 * c - x2 * sn;
    const float y2 = x2 * c + x1 * sn;
    const unsigned short h1 = f2bf(y1), h2 = f2bf(y2);
    Kh[b + d] = h1;       Kl[b + d] = f2bf(y1 - bf2f(h1));
    Kh[b + d + 64] = h2;  Kl[b + d + 64] = f2bf(y2 - bf2f(h2));
  }
}

// ---------------------------------------------------------------------------
// MFMA flash attention (causal GQA).
// Grid (32 qb, 32 h), 256 threads = 4 waves; wave w owns q rows qb*64+w*16..+15.
// K-tiles of 64. QK^T: 3-MFMA hi/lo split. P: bf16 via LDS.
// PV: P @ (Vh+Vl), V pre-transposed per kv-head as Vt[d][s].
// ---------------------------------------------------------------------------
#define KSTR 136  // 128+8 shorts
#define VSTR 72   // 64+8 shorts

__global__ __launch_bounds__(256, 2) void attn_mfma(
    const unsigned short* __restrict__ Qh, const unsigned short* __restrict__ Ql,
    const unsigned short* __restrict__ Kh, const unsigned short* __restrict__ Kl,
    const unsigned short* __restrict__ Vth, const unsigned short* __restrict__ Vtl,
    float* __restrict__ O) {
  __shared__ unsigned short sKh[64 * KSTR];
  __shared__ unsigned short sKl[64 * KSTR];
  __shared__ unsigned short sVh[128 * VSTR];
  __shared__ unsigned short sVl[128 * VSTR];
  __shared__ unsigned short sP[64 * VSTR];

  const int qb = 31 - blockIdx.x;  // heavy blocks dispatch first
  const int h = blockIdx.y;
  const int hk = h >> 2;
  const int t = threadIdx.x;
  const int lane = t & 63;
  const int w = t >> 6;
  const int lr = lane & 15;
  const int kg = (lane >> 4) * 8;

  // Q fragments (resident)
  short8 qa_h[4], qa_l[4];
  {
    const size_t qoff = (size_t)(qb * 64 + w * 16 + lr) * (NUM_HEADS * HEAD_DIM) + h * HEAD_DIM;
#pragma unroll
    for (int ks = 0; ks < 4; ++ks) {
      qa_h[ks] = *reinterpret_cast<const short8*>(&Qh[qoff + ks * 32 + kg]);
      qa_l[ks] = *reinterpret_cast<const short8*>(&Ql[qoff + ks * 32 + kg]);
    }
  }

  f32x4 acc_o[8] = {};
  float m_r[4], l_r[4];
#pragma unroll
  for (int r = 0; r < 4; ++r) { m_r[r] = -3.0e38f; l_r[r] = 0.0f; }

  const float scale = 0.08838834764831845f;  // 128^-0.5

  for (int kt = 0; kt <= qb; ++kt) {
    __syncthreads();
    // ---- stage K tile (hi/lo): 64 rows x 128 shorts each ----
#pragma unroll
    for (int i = 0; i < 4; ++i) {
      const int c = i * 256 + t;
      const int row = c >> 4, c8 = (c & 15) << 3;
      const size_t g = (size_t)(kt * 64 + row) * (NUM_KV_HEADS * HEAD_DIM) + hk * HEAD_DIM + c8;
      *reinterpret_cast<short8*>(&sKh[row * KSTR + c8]) =
          *reinterpret_cast<const short8*>(&Kh[g]);
      *reinterpret_cast<short8*>(&sKl[row * KSTR + c8]) =
          *reinterpret_cast<const short8*>(&Kl[g]);
    }
    // ---- stage Vt tile (hi/lo): 128 d-rows x 64 shorts each ----
#pragma unroll
    for (int i = 0; i < 4; ++i) {
      const int c = i * 256 + t;
      const int d = c >> 3, c8 = (c & 7) << 3;
      const size_t g = (size_t)(hk * HEAD_DIM + d) * S_LEN + kt * 64 + c8;
      *reinterpret_cast<short8*>(&sVh[d * VSTR + c8]) =
          *reinterpret_cast<const short8*>(&Vth[g]);
      *reinterpret_cast<short8*>(&sVl[d * VSTR + c8]) =
          *reinterpret_cast<const short8*>(&Vtl[g]);
    }
    __syncthreads();

    // ---- QK^T: S[16 q][64 k] per wave, hi/lo split ----
    f32x4 s_acc[4] = {};
#pragma unroll
    for (int j = 0; j < 4; ++j) {
      short8 kb_h[4], kb_l[4];
#pragma unroll
      for (int ks = 0; ks < 4; ++ks) {
        const int off = (j * 16 + lr) * KSTR + ks * 32 + kg;
        kb_h[ks] = *reinterpret_cast<const short8*>(&sKh[off]);
        kb_l[ks] = *reinterpret_cast<const short8*>(&sKl[off]);
      }
#pragma unroll
      for (int ks = 0; ks < 4; ++ks) {
        s_acc[j] = __builtin_amdgcn_mfma_f32_16x16x32_bf16(qa_h[ks], kb_h[ks], s_acc[j], 0, 0, 0);
        s_acc[j] = __builtin_amdgcn_mfma_f32_16x16x32_bf16(qa_h[ks], kb_l[ks], s_acc[j], 0, 0, 0);
        s_acc[j] = __builtin_amdgcn_mfma_f32_16x16x32_bf16(qa_l[ks], kb_h[ks], s_acc[j], 0, 0, 0);
      }
    }

    // ---- online softmax (C-layout: row=(lane>>4)*4+r, col=lane&15) ----
    const bool last = (kt == qb);
#pragma unroll
    for (int r = 0; r < 4; ++r) {
      const int qg = qb * 64 + w * 16 + (lane >> 4) * 4 + r;
      float sc[4];
#pragma unroll
      for (int j = 0; j < 4; ++j) sc[j] = s_acc[j][r] * scale;
      if (last) {
#pragma unroll
        for (int j = 0; j < 4; ++j) {
          const int kgl = kt * 64 + j * 16 + lr;
          if (kgl > qg) sc[j] += NEG;
        }
      }
      float mx = fmaxf(fmaxf(sc[0], sc[1]), fmaxf(sc[2], sc[3]));
#pragma unroll
      for (int off = 1; off < 16; off <<= 1) mx = fmaxf(mx, __shfl_xor(mx, off, 16));
      const float mnew = fmaxf(m_r[r], mx);
      float p[4], su = 0.0f;
#pragma unroll
      for (int j = 0; j < 4; ++j) { p[j] = __expf(sc[j] - mnew); su += p[j]; }
#pragma unroll
      for (int off = 1; off < 16; off <<= 1) su += __shfl_xor(su, off, 16);
      const float rs = __expf(m_r[r] - mnew);
      l_r[r] = l_r[r] * rs + su;
      m_r[r] = mnew;
#pragma unroll
      for (int df = 0; df < 8; ++df) acc_o[df][r] *= rs;
      const int prow = (w * 16 + (lane >> 4) * 4 + r) * VSTR;
#pragma unroll
      for (int j = 0; j < 4; ++j) sP[prow + j * 16 + lr] = f2bf(p[j]);
    }
    __syncthreads();

    // ---- PV: O[16 q][128 d] += P[16][64] @ Vt^T ----
    short8 pa[2];
#pragma unroll
    for (int ks = 0; ks < 2; ++ks)
      pa[ks] = *reinterpret_cast<const short8*>(&sP[(w * 16 + lr) * VSTR + ks * 32 + kg]);
#pragma unroll
    for (int df = 0; df < 8; ++df) {
#pragma unroll
      for (int ks = 0; ks < 2; ++ks) {
        const int off = (df * 16 + lr) * VSTR + ks * 32 + kg;
        const short8 vb_h = *reinterpret_cast<const short8*>(&sVh[off]);
        const short8 vb_l = *reinterpret_cast<const short8*>(&sVl[off]);
        acc_o[df] = __builtin_amdgcn_mfma_f32_16x16x32_bf16(pa[ks], vb_h, acc_o[df], 0, 0, 0);
        acc_o[df] = __builtin_amdgcn_mfma_f32_16x16x32_bf16(pa[ks], vb_l, acc_o[df], 0, 0, 0);
      }
    }
  }

  // ---- epilogue: normalize + store ----
#pragma unroll
  for (int r = 0; r < 4; ++r) {
    const int row = qb * 64 + w * 16 + (lane >> 4) * 4 + r;
    const float inv = 1.0f / l_r[r];
#pragma unroll
    for (int df = 0; df < 8; ++df)
      O[(size_t)row * (NUM_HEADS * HEAD_DIM) + h * HEAD_DIM + df * 16 + lr] =
          acc_o[df][r] * inv;
  }
}

// ---------------------------------------------------------------------------
// fallback fp32 GEMM + attention (only if ws too small)
// ---------------------------------------------------------------------------
#define TM 64
#define TN 64
#define TK 16

__global__ __launch_bounds__(256) void gemm_f32(const float* __restrict__ A,
                                                const float* __restrict__ B,
                                                float* __restrict__ C,
                                                int M, int N, int K) {
  __shared__ float As[TK][TM + 1];
  __shared__ float Bs[TK][TN + 1];
  const int t = threadIdx.x;
  const int bm = blockIdx.y * TM;
  const int bn = blockIdx.x * TN;
  const int tx = t & 15, ty = t >> 4;
  float acc[4][4] = {};
  for (int k0 = 0; k0 < K; k0 += TK) {
    {
      const int row = t >> 2;
      const int c4 = (t & 3) << 2;
      const float4 a4 = *reinterpret_cast<const float4*>(&A[(size_t)(bm + row) * K + k0 + c4]);
      As[c4 + 0][row] = a4.x; As[c4 + 1][row] = a4.y;
      As[c4 + 2][row] = a4.z; As[c4 + 3][row] = a4.w;
    }
    {
      const int row = t >> 4;
      const int c4 = (t & 15) << 2;
      const float4 b4 = *reinterpret_cast<const float4*>(&B[(size_t)(k0 + row) * N + bn + c4]);
      Bs[row][c4 + 0] = b4.x; Bs[row][c4 + 1] = b4.y;
      Bs[row][c4 + 2] = b4.z; Bs[row][c4 + 3] = b4.w;
    }
    __syncthreads();
#pragma unroll
    for (int kk = 0; kk < TK; ++kk) {
      float a[4], b[4];
#pragma unroll
      for (int i = 0; i < 4; ++i) a[i] = As[kk][ty * 4 + i];
#pragma unroll
      for (int j = 0; j < 4; ++j) b[j] = Bs[kk][tx * 4 + j];
#pragma unroll
      for (int i = 0; i < 4; ++i)
#pragma unroll
        for (int j = 0; j < 4; ++j) acc[i][j] += a[i] * b[j];
    }
    __syncthreads();
  }
#pragma unroll
  for (int i = 0; i < 4; ++i) {
    const int row = bm + ty * 4 + i;
#pragma unroll
    for (int j = 0; j < 4; ++j)
      C[(size_t)row * N + bn + tx * 4 + j] = acc[i][j];
  }
}

__global__ void rope_kernel(float* __restrict__ q, float* __restrict__ k,
                            const int* __restrict__ pos_ids) {
  const int idx = blockIdx.x * 256 + threadIdx.x;
  const int d = idx & 63;
  const int rest = idx >> 6;
  const int head = rest % (NUM_HEADS + NUM_KV_HEADS);
  const int s = rest / (NUM_HEADS + NUM_KV_HEADS);
  if (s >= S_LEN) return;
  const float pos = (float)pos_ids[s];
  const float inv = powf(10000.0f, -(float)d / 64.0f);
  const float ang = pos * inv;
  const float c = cosf(ang);
  const float sn = sinf(ang);
  float* base = (head < NUM_HEADS)
                    ? (q + (size_t)s * (NUM_HEADS * HEAD_DIM) + head * HEAD_DIM)
                    : (k + (size_t)s * (NUM_KV_HEADS * HEAD_DIM) + (head - NUM_HEADS) * HEAD_DIM);
  const float x1 = base[d];
  const float x2 = base[d + 64];
  base[d] = x1 * c - x2 * sn;
  base[d + 64] = x2 * c + x1 * sn;
}

#define QB 64
#define KT 32
#define PD 132

__global__ __launch_bounds__(256) void attn_kernel(
    const float* __restrict__ Q, const float* __restrict__ K,
    const float* __restrict__ V, float* __restrict__ O) {
  __shared__ float Qs[QB][PD];
  __shared__ float KVs[KT][PD];
  __shared__ float Ps[QB][KT + 2];
  const int qb = blockIdx.x;
  const int h = blockIdx.y;
  const int hk = h >> 2;
  const int t = threadIdx.x;
  const int tx = t & 15, ty = t >> 4;
#pragma unroll
  for (int r = 0; r < 8; ++r) {
    const int idx = r * 256 + t;
    const int row = idx >> 5;
    const int c4 = (idx & 31) << 2;
    *reinterpret_cast<float4*>(&Qs[row][c4]) = *reinterpret_cast<const float4*>(
        &Q[(size_t)(qb * QB + row) * (NUM_HEADS * HEAD_DIM) + h * HEAD_DIM + c4]);
  }
  float acc[4][8] = {};
  float mrow[4], lrow[4];
#pragma unroll
  for (int i = 0; i < 4; ++i) { mrow[i] = -3.0e38f; lrow[i] = 0.0f; }
  const float scale = 0.08838834764831845f;
  const int ktiles = 2 * qb + 2;
  for (int kt = 0; kt < ktiles; ++kt) {
    __syncthreads();
#pragma unroll
    for (int r = 0; r < 4; ++r) {
      const int idx = r * 256 + t;
      const int row = idx >> 5;
      const int c4 = (idx & 31) << 2;
      *reinterpret_cast<float4*>(&KVs[row][c4]) = *reinterpret_cast<const float4*>(
          &K[(size_t)(kt * KT + row) * (NUM_KV_HEADS * HEAD_DIM) + hk * HEAD_DIM + c4]);
    }
    __syncthreads();
    float sc[4][2] = {};
    for (int d4 = 0; d4 < HEAD_DIM; d4 += 4) {
      float4 a[4], b[2];
#pragma unroll
      for (int i = 0; i < 4; ++i) a[i] = *reinterpret_cast<const float4*>(&Qs[ty * 4 + i][d4]);
#pragma unroll
      for (int j = 0; j < 2; ++j) b[j] = *reinterpret_cast<const float4*>(&KVs[tx * 2 + j][d4]);
#pragma unroll
      for (int i = 0; i < 4; ++i)
#pragma unroll
        for (int j = 0; j < 2; ++j)
          sc[i][j] += a[i].x * b[j].x + a[i].y * b[j].y + a[i].z * b[j].z + a[i].w * b[j].w;
    }
    const bool need_mask = (kt * KT + KT - 1) > (qb * QB);
#pragma unroll
    for (int i = 0; i < 4; ++i) {
      const int qg = qb * QB + ty * 4 + i;
#pragma unroll
      for (int j = 0; j < 2; ++j) {
        float v = sc[i][j] * scale;
        if (need_mask) {
          const int kgl = kt * KT + tx * 2 + j;
          if (kgl > qg) v += NEG;
        }
        sc[i][j] = v;
      }
    }
#pragma unroll
    for (int i = 0; i < 4; ++i) {
      float mx = fmaxf(sc[i][0], sc[i][1]);
#pragma unroll
      for (int off = 1; off < 16; off <<= 1) mx = fmaxf(mx, __shfl_xor(mx, off, 16));
      const float mnew = fmaxf(mrow[i], mx);
      const float p0 = __expf(sc[i][0] - mnew);
      const float p1 = __expf(sc[i][1] - mnew);
      float su = p0 + p1;
#pragma unroll
      for (int off = 1; off < 16; off <<= 1) su += __shfl_xor(su, off, 16);
      const float rsc = __expf(mrow[i] - mnew);
      lrow[i] = lrow[i] * rsc + su;
      mrow[i] = mnew;
#pragma unroll
      for (int j = 0; j < 8; ++j) acc[i][j] *= rsc;
      Ps[ty * 4 + i][tx * 2 + 0] = p0;
      Ps[ty * 4 + i][tx * 2 + 1] = p1;
    }
    __syncthreads();
#pragma unroll
    for (int r = 0; r < 4; ++r) {
      const int idx = r * 256 + t;
      const int row = idx >> 5;
      const int c4 = (idx & 31) << 2;
      *reinterpret_cast<float4*>(&KVs[row][c4]) = *reinterpret_cast<const float4*>(
          &V[(size_t)(kt * KT + row) * (NUM_KV_HEADS * HEAD_DIM) + hk * HEAD_DIM + c4]);
    }
    __syncthreads();
    for (int kk = 0; kk < KT; ++kk) {
      const float4 b0 = *reinterpret_cast<const float4*>(&KVs[kk][tx * 8]);
      const float4 b1 = *reinterpret_cast<const float4*>(&KVs[kk][tx * 8 + 4]);
#pragma unroll
      for (int i = 0; i < 4; ++i) {
        const float p = Ps[ty * 4 + i][kk];
        acc[i][0] += p * b0.x; acc[i][1] += p * b0.y;
        acc[i][2] += p * b0.z; acc[i][3] += p * b0.w;
        acc[i][4] += p * b1.x; acc[i][5] += p * b1.y;
        acc[i][6] += p * b1.z; acc[i][7] += p * b1.w;
      }
    }
  }
#pragma unroll
  for (int i = 0; i < 4; ++i) {
    const int row = qb * QB + ty * 4 + i;
    const float inv = 1.0f / lrow[i];
#pragma unroll
    for (int j = 0; j < 8; ++j)
      O[(size_t)row * (NUM_HEADS * HEAD_DIM) + h * HEAD_DIM + tx * 8 + j] = acc[i][j] * inv;
  }
}

// ---------------------------------------------------------------------------
// launch
// ---------------------------------------------------------------------------
extern "C" void kernel_launch(void* const* d_in, const int* in_sizes, int n_in,
                              void* d_out, int out_size, void* d_ws,
                              size_t ws_size, hipStream_t stream) {
  const float* hidden = (const float*)d_in[0];
  const int* pos_ids = (const int*)d_in[2];
  const float* Wq = (const float*)d_in[3];
  const float* Wk = (const float*)d_in[4];
  const float* Wv = (const float*)d_in[5];
  const float* Wo = (const float*)d_in[6];
  float* out = (float*)d_out;

  char* ws = (char*)d_ws;
  const size_t SZ_Q = (size_t)S_LEN * HIDDEN * 4;    // 32 MB
  const size_t SZ_KV = (size_t)S_LEN * 1024 * 4;     // 8 MB
  const size_t SZ_AH = (size_t)S_LEN * HIDDEN * 2;   // 16 MB
  const size_t SZ_WH = (size_t)HIDDEN * HIDDEN * 2;  // 32 MB
  const size_t MB = (size_t)1 << 20;

  float* q = (float*)(ws);                                    // [0, 32M)
  float* k = (float*)(ws + SZ_Q);                             // [32, 40)
  float* v = (float*)(ws + SZ_Q + SZ_KV);                     // [40, 48)
  float* ao_fb = (float*)(ws + SZ_Q + 2 * SZ_KV);             // [48, 80) fallback only
  unsigned short* Ah = (unsigned short*)(ws + 2 * SZ_Q + 2 * SZ_KV);            // [80, 96)
  unsigned short* Al = (unsigned short*)(ws + 2 * SZ_Q + 2 * SZ_KV + SZ_AH);    // [96, 112)
  char* whbase = ws + 2 * SZ_Q + 2 * SZ_KV + 2 * SZ_AH;                         // [112, 176)
  unsigned short* Wh = (unsigned short*)(whbase);
  unsigned short* Wl = (unsigned short*)(whbase + SZ_WH);
  const size_t needed = 2 * SZ_Q + 2 * SZ_KV + 2 * SZ_AH + 2 * SZ_WH;  // 176 MB

  // MFMA-path aliases (within 176 MB; lifetimes disjoint):
  unsigned short* Qhb = Ah;                                   // 16 MB
  unsigned short* Qlb = Al;                                   // 16 MB
  unsigned short* Khb = (unsigned short*)(whbase);            // 4 MB
  unsigned short* Klb = (unsigned short*)(whbase + 4 * MB);   // 4 MB
  unsigned short* Vth = (unsigned short*)(whbase + 8 * MB);   // 4 MB
  unsigned short* Vtl = (unsigned short*)(whbase + 12 * MB);  // 4 MB
  float* ao = q;  // attn out aliases dead q fp32

  if (ws_size >= needed) {
    const int n4_hidden = S_LEN * HIDDEN / 4;
    split_mat<<<(n4_hidden + 255) / 256, 256, 0, stream>>>(hidden, Ah, Al, n4_hidden);
    split_transpose<<<dim3(HIDDEN / 32, HIDDEN / 32), 256, 0, stream>>>(Wq, Wh, Wl, HIDDEN, HIDDEN);
    gemm_split<<<dim3(HIDDEN / BN, S_LEN / BM), 256, 0, stream>>>(Ah, Al, Wh, Wl, q, S_LEN, HIDDEN, HIDDEN);
    split_transpose<<<dim3(1024 / 32, HIDDEN / 32), 256, 0, stream>>>(Wk, Wh, Wl, HIDDEN, 1024);
    gemm_split<<<dim3(1024 / BN, S_LEN / BM), 256, 0, stream>>>(Ah, Al, Wh, Wl, k, S_LEN, 1024, HIDDEN);
    split_transpose<<<dim3(1024 / 32, HIDDEN / 32), 256, 0, stream>>>(Wv, Wh, Wl, HIDDEN, 1024);
    gemm_split<<<dim3(1024 / BN, S_LEN / BM), 256, 0, stream>>>(Ah, Al, Wh, Wl, v, S_LEN, 1024, HIDDEN);

    // RoPE + bf16 split for Q/K (overwrites Ah/Al and Wh-region — both dead)
    {
      const int total = S_LEN * (NUM_HEADS + NUM_KV_HEADS) * 64;
      rope_convert<<<(total + 255) / 256, 256, 0, stream>>>(q, k, pos_ids, Qhb, Qlb, Khb, Klb);
    }
    // V -> transposed bf16 hi/lo: Vt[1024 dglobal][2048 s]
    split_transpose<<<dim3(1024 / 32, S_LEN / 32), 256, 0, stream>>>(v, Vth, Vtl, S_LEN, 1024);

    // attention
    attn_mfma<<<dim3(32, NUM_HEADS), 256, 0, stream>>>(Qhb, Qlb, Khb, Klb, Vth, Vtl, ao);

    // output projection
    split_mat<<<(n4_hidden + 255) / 256, 256, 0, stream>>>(ao, Ah, Al, n4_hidden);
    split_transpose<<<dim3(HIDDEN / 32, HIDDEN / 32), 256, 0, stream>>>(Wo, Wh, Wl, HIDDEN, HIDDEN);
    gemm_split<<<dim3(HIDDEN / BN, S_LEN / BM), 256, 0, stream>>>(Ah, Al, Wh, Wl, out, S_LEN, HIDDEN, HIDDEN);
  } else {
    gemm_f32<<<dim3(HIDDEN / TN, S_LEN / TM), 256, 0, stream>>>(hidden, Wq, q, S_LEN, HIDDEN, HIDDEN);
    gemm_f32<<<dim3(1024 / TN, S_LEN / TM), 256, 0, stream>>>(hidden, Wk, k, S_LEN, 1024, HIDDEN);
    gemm_f32<<<dim3(1024 / TN, S_LEN / TM), 256, 0, stream>>>(hidden, Wv, v, S_LEN, 1024, HIDDEN);
    {
      const int total = S_LEN * (NUM_HEADS + NUM_KV_HEADS) * 64;
      rope_kernel<<<(total + 255) / 256, 256, 0, stream>>>(q, k, pos_ids);
    }
    attn_kernel<<<dim3(S_LEN / QB, NUM_HEADS), 256, 0, stream>>>(q, k, v, ao_fb);
    gemm_f32<<<dim3(HIDDEN / TN, S_LEN / TM), 256, 0, stream>>>(ao_fb, Wo, out, S_LEN, HIDDEN, HIDDEN);
  }
}

// Round 7
// 1077.943 us; speedup vs baseline: 4.9972x; 1.1513x over previous
//
#include <hip/hip_runtime.h>
#include <math.h>

#define S_LEN 2048
#define HIDDEN 4096
#define NUM_HEADS 32
#define NUM_KV_HEADS 8
#define HEAD_DIM 128
#define NEG (-1e9f)

using short8 = __attribute__((ext_vector_type(8))) short;
using f32x4 = __attribute__((ext_vector_type(4))) float;

// ---------------------------------------------------------------------------
// helpers
// ---------------------------------------------------------------------------
__device__ inline unsigned short f2bf(float f) {
  union { float f; unsigned u; } c;
  c.f = f;
  unsigned r = c.u + 0x7fffu + ((c.u >> 16) & 1u);  // RNE
  return (unsigned short)(r >> 16);
}
__device__ inline float bf2f(unsigned short h) {
  union { unsigned u; float f; } c;
  c.u = ((unsigned)h) << 16;
  return c.f;
}
__device__ inline void gload16(const void* g, void* l) {
  __builtin_amdgcn_global_load_lds(
      (const __attribute__((address_space(1))) unsigned*)g,
      (__attribute__((address_space(3))) unsigned*)l, 16, 0, 0);
}

// ---------------------------------------------------------------------------
// split fp32 -> (hi, lo) bf16, elementwise
// ---------------------------------------------------------------------------
__global__ __launch_bounds__(256) void split_mat(const float* __restrict__ X,
                                                 unsigned short* __restrict__ Xh,
                                                 unsigned short* __restrict__ Xl,
                                                 int n4) {
  const int i = blockIdx.x * 256 + threadIdx.x;
  if (i >= n4) return;
  const float4 x = *reinterpret_cast<const float4*>(&X[(size_t)i * 4]);
  ushort4 h, l;
  h.x = f2bf(x.x); l.x = f2bf(x.x - bf2f(h.x));
  h.y = f2bf(x.y); l.y = f2bf(x.y - bf2f(h.y));
  h.z = f2bf(x.z); l.z = f2bf(x.z - bf2f(h.z));
  h.w = f2bf(x.w); l.w = f2bf(x.w - bf2f(h.w));
  *reinterpret_cast<ushort4*>(&Xh[(size_t)i * 4]) = h;
  *reinterpret_cast<ushort4*>(&Xl[(size_t)i * 4]) = l;
}

// ---------------------------------------------------------------------------
// split + transpose: B[K][N] (row stride ldb) fp32 -> Th[N][K], Tl[N][K] bf16
// ---------------------------------------------------------------------------
__global__ __launch_bounds__(256) void split_transpose(
    const float* __restrict__ B, unsigned short* __restrict__ Th,
    unsigned short* __restrict__ Tl, int K, int N, int ldb) {
  __shared__ float ts[32][33];
  const int t = threadIdx.x;
  const int k0 = blockIdx.y * 32, n0 = blockIdx.x * 32;
  const int r = t >> 3, c4 = (t & 7) << 2;
  const float4 x = *reinterpret_cast<const float4*>(&B[(size_t)(k0 + r) * ldb + n0 + c4]);
  ts[r][c4 + 0] = x.x;
  ts[r][c4 + 1] = x.y;
  ts[r][c4 + 2] = x.z;
  ts[r][c4 + 3] = x.w;
  __syncthreads();
  const int col = r, ks = c4;
  ushort4 h, l;
#pragma unroll
  for (int e = 0; e < 4; ++e) {
    const float v = ts[ks + e][col];
    const unsigned short hh = f2bf(v);
    const unsigned short ll = f2bf(v - bf2f(hh));
    ((unsigned short*)&h)[e] = hh;
    ((unsigned short*)&l)[e] = ll;
  }
  *reinterpret_cast<ushort4*>(&Th[(size_t)(n0 + col) * K + k0 + ks]) = h;
  *reinterpret_cast<ushort4*>(&Tl[(size_t)(n0 + col) * K + k0 + ks]) = l;
}

// ---------------------------------------------------------------------------
// Split-bf16 MFMA GEMM (verified round 2): C = (Ah+Al) @ (Bh+Bl)^T
// ---------------------------------------------------------------------------
#define BM 128
#define BN 128
#define BK 32

__global__ __launch_bounds__(256) void gemm_split(
    const unsigned short* __restrict__ Ah, const unsigned short* __restrict__ Al,
    const unsigned short* __restrict__ Bh, const unsigned short* __restrict__ Bl,
    float* __restrict__ C, int M, int N, int K) {
  __shared__ unsigned short sAh[BM * BK];
  __shared__ unsigned short sAl[BM * BK];
  __shared__ unsigned short sBh[BN * BK];
  __shared__ unsigned short sBl[BN * BK];

  const int t = threadIdx.x;
  const int lane = t & 63;
  const int w = t >> 6;
  const int bm = blockIdx.y * BM;
  const int bn = blockIdx.x * BN;
  const int wr = (w >> 1) * 64;
  const int wc = (w & 1) * 64;

  f32x4 acc[4][4] = {};

  const int lrow = lane & 15;
  const int kg = (lane >> 4) * 8;

  for (int k0 = 0; k0 < K; k0 += BK) {
    __syncthreads();
#pragma unroll
    for (int cc = 0; cc < 2; ++cc) {
      const int c = t + cc * 256;
      const int row = c >> 2, kk = (c & 3) * 8;
      const size_t ga = (size_t)(bm + row) * K + k0 + kk;
      const size_t gb = (size_t)(bn + row) * K + k0 + kk;
      gload16(Ah + ga, &sAh[c * 8]);
      gload16(Al + ga, &sAl[c * 8]);
      gload16(Bh + gb, &sBh[c * 8]);
      gload16(Bl + gb, &sBl[c * 8]);
    }
    __syncthreads();

    short8 ah[4], al[4], bh[4], bl[4];
#pragma unroll
    for (int i = 0; i < 4; ++i) {
      const int ar = (wr + i * 16 + lrow) * BK + kg;
      ah[i] = *reinterpret_cast<const short8*>(&sAh[ar]);
      al[i] = *reinterpret_cast<const short8*>(&sAl[ar]);
      const int br = (wc + i * 16 + lrow) * BK + kg;
      bh[i] = *reinterpret_cast<const short8*>(&sBh[br]);
      bl[i] = *reinterpret_cast<const short8*>(&sBl[br]);
    }
#pragma unroll
    for (int i = 0; i < 4; ++i)
#pragma unroll
      for (int j = 0; j < 4; ++j) {
        acc[i][j] = __builtin_amdgcn_mfma_f32_16x16x32_bf16(ah[i], bh[j], acc[i][j], 0, 0, 0);
        acc[i][j] = __builtin_amdgcn_mfma_f32_16x16x32_bf16(ah[i], bl[j], acc[i][j], 0, 0, 0);
        acc[i][j] = __builtin_amdgcn_mfma_f32_16x16x32_bf16(al[i], bh[j], acc[i][j], 0, 0, 0);
      }
  }

#pragma unroll
  for (int i = 0; i < 4; ++i) {
    const int row0 = bm + wr + i * 16 + (lane >> 4) * 4;
#pragma unroll
    for (int j = 0; j < 4; ++j) {
      const int col = bn + wc + j * 16 + (lane & 15);
#pragma unroll
      for (int r = 0; r < 4; ++r)
        C[(size_t)(row0 + r) * N + col] = acc[i][j][r];
    }
  }
}

// ---------------------------------------------------------------------------
// RoPE + split-to-bf16(hi/lo). q from q-buffer (stride 4096); k from the
// fused kv buffer (row stride kld, k at col offset 0). Outputs compact.
// ---------------------------------------------------------------------------
__global__ void rope_convert(const float* __restrict__ q, const float* __restrict__ kv,
                             int kld, const int* __restrict__ pos_ids,
                             unsigned short* __restrict__ Qh, unsigned short* __restrict__ Ql,
                             unsigned short* __restrict__ Kh, unsigned short* __restrict__ Kl) {
  const int idx = blockIdx.x * 256 + threadIdx.x;
  const int d = idx & 63;
  const int rest = idx >> 6;
  const int head = rest % (NUM_HEADS + NUM_KV_HEADS);
  const int s = rest / (NUM_HEADS + NUM_KV_HEADS);
  if (s >= S_LEN) return;

  const float pos = (float)pos_ids[s];
  const float inv = powf(10000.0f, -(float)d / 64.0f);
  const float ang = pos * inv;
  const float c = cosf(ang);
  const float sn = sinf(ang);

  if (head < NUM_HEADS) {
    const size_t b = (size_t)s * (NUM_HEADS * HEAD_DIM) + head * HEAD_DIM;
    const float x1 = q[b + d], x2 = q[b + d + 64];
    const float y1 = x1 * c - x2 * sn;
    const float y2 = x2 * c + x1 * sn;
    const unsigned short h1 = f2bf(y1), h2 = f2bf(y2);
    Qh[b + d] = h1;       Ql[b + d] = f2bf(y1 - bf2f(h1));
    Qh[b + d + 64] = h2;  Ql[b + d + 64] = f2bf(y2 - bf2f(h2));
  } else {
    const int kh = head - NUM_HEADS;
    const size_t gsrc = (size_t)s * kld + kh * HEAD_DIM;
    const size_t b = (size_t)s * (NUM_KV_HEADS * HEAD_DIM) + kh * HEAD_DIM;
    const float x1 = kv[gsrc + d], x2 = kv[gsrc + d + 64];
    const float y1 = x1 * c - x2 * sn;
    const float y2 = x2 * c + x1 * sn;
    const unsigned short h1 = f2bf(y1), h2 = f2bf(y2);
    Kh[b + d] = h1;       Kl[b + d] = f2bf(y1 - bf2f(h1));
    Kh[b + d + 64] = h2;  Kl[b + d + 64] = f2bf(y2 - bf2f(h2));
  }
}

// ---------------------------------------------------------------------------
// MFMA flash attention (causal GQA).
// Grid (32 qb, 32 h), 256 threads = 4 waves; wave w owns q rows qb*64+w*16..+15.
// K-tiles of 64. QK^T: 3-MFMA hi/lo split. P: hi/lo bf16 (exact-ish).
// PV: (Ph+Pl) @ V, V single bf16 pre-transposed per kv-head as Vt[d][s].
// ---------------------------------------------------------------------------
#define KSTR 136  // 128+8 shorts
#define VSTR 72   // 64+8 shorts

__global__ __launch_bounds__(256, 2) void attn_mfma(
    const unsigned short* __restrict__ Qh, const unsigned short* __restrict__ Ql,
    const unsigned short* __restrict__ Kh, const unsigned short* __restrict__ Kl,
    const unsigned short* __restrict__ Vth, float* __restrict__ O) {
  __shared__ unsigned short sKh[64 * KSTR];
  __shared__ unsigned short sKl[64 * KSTR];
  __shared__ unsigned short sVh[128 * VSTR];
  __shared__ unsigned short sPh[64 * VSTR];
  __shared__ unsigned short sPl[64 * VSTR];

  const int qb = 31 - blockIdx.x;  // heavy blocks dispatch first
  const int h = blockIdx.y;
  const int hk = h >> 2;
  const int t = threadIdx.x;
  const int lane = t & 63;
  const int w = t >> 6;
  const int lr = lane & 15;
  const int kg = (lane >> 4) * 8;

  // Q fragments (resident)
  short8 qa_h[4], qa_l[4];
  {
    const size_t qoff = (size_t)(qb * 64 + w * 16 + lr) * (NUM_HEADS * HEAD_DIM) + h * HEAD_DIM;
#pragma unroll
    for (int ks = 0; ks < 4; ++ks) {
      qa_h[ks] = *reinterpret_cast<const short8*>(&Qh[qoff + ks * 32 + kg]);
      qa_l[ks] = *reinterpret_cast<const short8*>(&Ql[qoff + ks * 32 + kg]);
    }
  }

  f32x4 acc_o[8] = {};
  float m_r[4], l_r[4];
#pragma unroll
  for (int r = 0; r < 4; ++r) { m_r[r] = -3.0e38f; l_r[r] = 0.0f; }

  const float scale = 0.08838834764831845f;  // 128^-0.5

  for (int kt = 0; kt <= qb; ++kt) {
    __syncthreads();
    // ---- stage K tile (hi/lo): 64 rows x 128 shorts each ----
#pragma unroll
    for (int i = 0; i < 4; ++i) {
      const int c = i * 256 + t;
      const int row = c >> 4, c8 = (c & 15) << 3;
      const size_t g = (size_t)(kt * 64 + row) * (NUM_KV_HEADS * HEAD_DIM) + hk * HEAD_DIM + c8;
      *reinterpret_cast<short8*>(&sKh[row * KSTR + c8]) =
          *reinterpret_cast<const short8*>(&Kh[g]);
      *reinterpret_cast<short8*>(&sKl[row * KSTR + c8]) =
          *reinterpret_cast<const short8*>(&Kl[g]);
    }
    // ---- stage Vt tile (single bf16): 128 d-rows x 64 shorts ----
#pragma unroll
    for (int i = 0; i < 4; ++i) {
      const int c = i * 256 + t;
      const int d = c >> 3, c8 = (c & 7) << 3;
      const size_t g = (size_t)(hk * HEAD_DIM + d) * S_LEN + kt * 64 + c8;
      *reinterpret_cast<short8*>(&sVh[d * VSTR + c8]) =
          *reinterpret_cast<const short8*>(&Vth[g]);
    }
    __syncthreads();

    // ---- QK^T: S[16 q][64 k] per wave, hi/lo split ----
    f32x4 s_acc[4] = {};
#pragma unroll
    for (int j = 0; j < 4; ++j) {
      short8 kb_h[4], kb_l[4];
#pragma unroll
      for (int ks = 0; ks < 4; ++ks) {
        const int off = (j * 16 + lr) * KSTR + ks * 32 + kg;
        kb_h[ks] = *reinterpret_cast<const short8*>(&sKh[off]);
        kb_l[ks] = *reinterpret_cast<const short8*>(&sKl[off]);
      }
#pragma unroll
      for (int ks = 0; ks < 4; ++ks) {
        s_acc[j] = __builtin_amdgcn_mfma_f32_16x16x32_bf16(qa_h[ks], kb_h[ks], s_acc[j], 0, 0, 0);
        s_acc[j] = __builtin_amdgcn_mfma_f32_16x16x32_bf16(qa_h[ks], kb_l[ks], s_acc[j], 0, 0, 0);
        s_acc[j] = __builtin_amdgcn_mfma_f32_16x16x32_bf16(qa_l[ks], kb_h[ks], s_acc[j], 0, 0, 0);
      }
    }

    // ---- online softmax (C-layout: row=(lane>>4)*4+r, col=lane&15) ----
    const bool last = (kt == qb);
#pragma unroll
    for (int r = 0; r < 4; ++r) {
      const int qg = qb * 64 + w * 16 + (lane >> 4) * 4 + r;
      float sc[4];
#pragma unroll
      for (int j = 0; j < 4; ++j) sc[j] = s_acc[j][r] * scale;
      if (last) {
#pragma unroll
        for (int j = 0; j < 4; ++j) {
          const int kgl = kt * 64 + j * 16 + lr;
          if (kgl > qg) sc[j] += NEG;
        }
      }
      float mx = fmaxf(fmaxf(sc[0], sc[1]), fmaxf(sc[2], sc[3]));
#pragma unroll
      for (int off = 1; off < 16; off <<= 1) mx = fmaxf(mx, __shfl_xor(mx, off, 16));
      const float mnew = fmaxf(m_r[r], mx);
      float p[4], su = 0.0f;
#pragma unroll
      for (int j = 0; j < 4; ++j) { p[j] = __expf(sc[j] - mnew); su += p[j]; }
#pragma unroll
      for (int off = 1; off < 16; off <<= 1) su += __shfl_xor(su, off, 16);
      const float rs = __expf(m_r[r] - mnew);
      l_r[r] = l_r[r] * rs + su;
      m_r[r] = mnew;
#pragma unroll
      for (int df = 0; df < 8; ++df) acc_o[df][r] *= rs;
      const int prow = (w * 16 + (lane >> 4) * 4 + r) * VSTR;
#pragma unroll
      for (int j = 0; j < 4; ++j) {
        const unsigned short ph = f2bf(p[j]);
        sPh[prow + j * 16 + lr] = ph;
        sPl[prow + j * 16 + lr] = f2bf(p[j] - bf2f(ph));
      }
    }
    __syncthreads();

    // ---- PV: O[16 q][128 d] += (Ph+Pl)[16][64] @ Vt^T ----
    short8 pa_h[2], pa_l[2];
#pragma unroll
    for (int ks = 0; ks < 2; ++ks) {
      const int off = (w * 16 + lr) * VSTR + ks * 32 + kg;
      pa_h[ks] = *reinterpret_cast<const short8*>(&sPh[off]);
      pa_l[ks] = *reinterpret_cast<const short8*>(&sPl[off]);
    }
#pragma unroll
    for (int df = 0; df < 8; ++df) {
#pragma unroll
      for (int ks = 0; ks < 2; ++ks) {
        const int off = (df * 16 + lr) * VSTR + ks * 32 + kg;
        const short8 vb = *reinterpret_cast<const short8*>(&sVh[off]);
        acc_o[df] = __builtin_amdgcn_mfma_f32_16x16x32_bf16(pa_h[ks], vb, acc_o[df], 0, 0, 0);
        acc_o[df] = __builtin_amdgcn_mfma_f32_16x16x32_bf16(pa_l[ks], vb, acc_o[df], 0, 0, 0);
      }
    }
  }

  // ---- epilogue: normalize + store ----
#pragma unroll
  for (int r = 0; r < 4; ++r) {
    const int row = qb * 64 + w * 16 + (lane >> 4) * 4 + r;
    const float inv = 1.0f / l_r[r];
#pragma unroll
    for (int df = 0; df < 8; ++df)
      O[(size_t)row * (NUM_HEADS * HEAD_DIM) + h * HEAD_DIM + df * 16 + lr] =
          acc_o[df][r] * inv;
  }
}

// ---------------------------------------------------------------------------
// fallback fp32 GEMM + attention (only if ws too small)
// ---------------------------------------------------------------------------
#define TM 64
#define TN 64
#define TK 16

__global__ __launch_bounds__(256) void gemm_f32(const float* __restrict__ A,
                                                const float* __restrict__ B,
                                                float* __restrict__ C,
                                                int M, int N, int K) {
  __shared__ float As[TK][TM + 1];
  __shared__ float Bs[TK][TN + 1];
  const int t = threadIdx.x;
  const int bm = blockIdx.y * TM;
  const int bn = blockIdx.x * TN;
  const int tx = t & 15, ty = t >> 4;
  float acc[4][4] = {};
  for (int k0 = 0; k0 < K; k0 += TK) {
    {
      const int row = t >> 2;
      const int c4 = (t & 3) << 2;
      const float4 a4 = *reinterpret_cast<const float4*>(&A[(size_t)(bm + row) * K + k0 + c4]);
      As[c4 + 0][row] = a4.x; As[c4 + 1][row] = a4.y;
      As[c4 + 2][row] = a4.z; As[c4 + 3][row] = a4.w;
    }
    {
      const int row = t >> 4;
      const int c4 = (t & 15) << 2;
      const float4 b4 = *reinterpret_cast<const float4*>(&B[(size_t)(k0 + row) * N + bn + c4]);
      Bs[row][c4 + 0] = b4.x; Bs[row][c4 + 1] = b4.y;
      Bs[row][c4 + 2] = b4.z; Bs[row][c4 + 3] = b4.w;
    }
    __syncthreads();
#pragma unroll
    for (int kk = 0; kk < TK; ++kk) {
      float a[4], b[4];
#pragma unroll
      for (int i = 0; i < 4; ++i) a[i] = As[kk][ty * 4 + i];
#pragma unroll
      for (int j = 0; j < 4; ++j) b[j] = Bs[kk][tx * 4 + j];
#pragma unroll
      for (int i = 0; i < 4; ++i)
#pragma unroll
        for (int j = 0; j < 4; ++j) acc[i][j] += a[i] * b[j];
    }
    __syncthreads();
  }
#pragma unroll
  for (int i = 0; i < 4; ++i) {
    const int row = bm + ty * 4 + i;
#pragma unroll
    for (int j = 0; j < 4; ++j)
      C[(size_t)row * N + bn + tx * 4 + j] = acc[i][j];
  }
}

__global__ void rope_kernel(float* __restrict__ q, float* __restrict__ k,
                            const int* __restrict__ pos_ids) {
  const int idx = blockIdx.x * 256 + threadIdx.x;
  const int d = idx & 63;
  const int rest = idx >> 6;
  const int head = rest % (NUM_HEADS + NUM_KV_HEADS);
  const int s = rest / (NUM_HEADS + NUM_KV_HEADS);
  if (s >= S_LEN) return;
  const float pos = (float)pos_ids[s];
  const float inv = powf(10000.0f, -(float)d / 64.0f);
  const float ang = pos * inv;
  const float c = cosf(ang);
  const float sn = sinf(ang);
  float* base = (head < NUM_HEADS)
                    ? (q + (size_t)s * (NUM_HEADS * HEAD_DIM) + head * HEAD_DIM)
                    : (k + (size_t)s * (NUM_KV_HEADS * HEAD_DIM) + (head - NUM_HEADS) * HEAD_DIM);
  const float x1 = base[d];
  const float x2 = base[d + 64];
  base[d] = x1 * c - x2 * sn;
  base[d + 64] = x2 * c + x1 * sn;
}

#define QB 64
#define KT 32
#define PD 132

__global__ __launch_bounds__(256) void attn_kernel(
    const float* __restrict__ Q, const float* __restrict__ K,
    const float* __restrict__ V, float* __restrict__ O) {
  __shared__ float Qs[QB][PD];
  __shared__ float KVs[KT][PD];
  __shared__ float Ps[QB][KT + 2];
  const int qb = blockIdx.x;
  const int h = blockIdx.y;
  const int hk = h >> 2;
  const int t = threadIdx.x;
  const int tx = t & 15, ty = t >> 4;
#pragma unroll
  for (int r = 0; r < 8; ++r) {
    const int idx = r * 256 + t;
    const int row = idx >> 5;
    const int c4 = (idx & 31) << 2;
    *reinterpret_cast<float4*>(&Qs[row][c4]) = *reinterpret_cast<const float4*>(
        &Q[(size_t)(qb * QB + row) * (NUM_HEADS * HEAD_DIM) + h * HEAD_DIM + c4]);
  }
  float acc[4][8] = {};
  float mrow[4], lrow[4];
#pragma unroll
  for (int i = 0; i < 4; ++i) { mrow[i] = -3.0e38f; lrow[i] = 0.0f; }
  const float scale = 0.08838834764831845f;
  const int ktiles = 2 * qb + 2;
  for (int kt = 0; kt < ktiles; ++kt) {
    __syncthreads();
#pragma unroll
    for (int r = 0; r < 4; ++r) {
      const int idx = r * 256 + t;
      const int row = idx >> 5;
      const int c4 = (idx & 31) << 2;
      *reinterpret_cast<float4*>(&KVs[row][c4]) = *reinterpret_cast<const float4*>(
          &K[(size_t)(kt * KT + row) * (NUM_KV_HEADS * HEAD_DIM) + hk * HEAD_DIM + c4]);
    }
    __syncthreads();
    float sc[4][2] = {};
    for (int d4 = 0; d4 < HEAD_DIM; d4 += 4) {
      float4 a[4], b[2];
#pragma unroll
      for (int i = 0; i < 4; ++i) a[i] = *reinterpret_cast<const float4*>(&Qs[ty * 4 + i][d4]);
#pragma unroll
      for (int j = 0; j < 2; ++j) b[j] = *reinterpret_cast<const float4*>(&KVs[tx * 2 + j][d4]);
#pragma unroll
      for (int i = 0; i < 4; ++i)
#pragma unroll
        for (int j = 0; j < 2; ++j)
          sc[i][j] += a[i].x * b[j].x + a[i].y * b[j].y + a[i].z * b[j].z + a[i].w * b[j].w;
    }
    const bool need_mask = (kt * KT + KT - 1) > (qb * QB);
#pragma unroll
    for (int i = 0; i < 4; ++i) {
      const int qg = qb * QB + ty * 4 + i;
#pragma unroll
      for (int j = 0; j < 2; ++j) {
        float v = sc[i][j] * scale;
        if (need_mask) {
          const int kgl = kt * KT + tx * 2 + j;
          if (kgl > qg) v += NEG;
        }
        sc[i][j] = v;
      }
    }
#pragma unroll
    for (int i = 0; i < 4; ++i) {
      float mx = fmaxf(sc[i][0], sc[i][1]);
#pragma unroll
      for (int off = 1; off < 16; off <<= 1) mx = fmaxf(mx, __shfl_xor(mx, off, 16));
      const float mnew = fmaxf(mrow[i], mx);
      const float p0 = __expf(sc[i][0] - mnew);
      const float p1 = __expf(sc[i][1] - mnew);
      float su = p0 + p1;
#pragma unroll
      for (int off = 1; off < 16; off <<= 1) su += __shfl_xor(su, off, 16);
      const float rsc = __expf(mrow[i] - mnew);
      lrow[i] = lrow[i] * rsc + su;
      mrow[i] = mnew;
#pragma unroll
      for (int j = 0; j < 8; ++j) acc[i][j] *= rsc;
      Ps[ty * 4 + i][tx * 2 + 0] = p0;
      Ps[ty * 4 + i][tx * 2 + 1] = p1;
    }
    __syncthreads();
#pragma unroll
    for (int r = 0; r < 4; ++r) {
      const int idx = r * 256 + t;
      const int row = idx >> 5;
      const int c4 = (idx & 31) << 2;
      *reinterpret_cast<float4*>(&KVs[row][c4]) = *reinterpret_cast<const float4*>(
          &V[(size_t)(kt * KT + row) * (NUM_KV_HEADS * HEAD_DIM) + hk * HEAD_DIM + c4]);
    }
    __syncthreads();
    for (int kk = 0; kk < KT; ++kk) {
      const float4 b0 = *reinterpret_cast<const float4*>(&KVs[kk][tx * 8]);
      const float4 b1 = *reinterpret_cast<const float4*>(&KVs[kk][tx * 8 + 4]);
#pragma unroll
      for (int i = 0; i < 4; ++i) {
        const float p = Ps[ty * 4 + i][kk];
        acc[i][0] += p * b0.x; acc[i][1] += p * b0.y;
        acc[i][2] += p * b0.z; acc[i][3] += p * b0.w;
        acc[i][4] += p * b1.x; acc[i][5] += p * b1.y;
        acc[i][6] += p * b1.z; acc[i][7] += p * b1.w;
      }
    }
  }
#pragma unroll
  for (int i = 0; i < 4; ++i) {
    const int row = qb * QB + ty * 4 + i;
    const float inv = 1.0f / lrow[i];
#pragma unroll
    for (int j = 0; j < 8; ++j)
      O[(size_t)row * (NUM_HEADS * HEAD_DIM) + h * HEAD_DIM + tx * 8 + j] = acc[i][j] * inv;
  }
}

// ---------------------------------------------------------------------------
// launch
// ---------------------------------------------------------------------------
extern "C" void kernel_launch(void* const* d_in, const int* in_sizes, int n_in,
                              void* d_out, int out_size, void* d_ws,
                              size_t ws_size, hipStream_t stream) {
  const float* hidden = (const float*)d_in[0];
  const int* pos_ids = (const int*)d_in[2];
  const float* Wq = (const float*)d_in[3];
  const float* Wk = (const float*)d_in[4];
  const float* Wv = (const float*)d_in[5];
  const float* Wo = (const float*)d_in[6];
  float* out = (float*)d_out;

  char* ws = (char*)d_ws;
  const size_t MB = (size_t)1 << 20;
  const size_t SZ_Q = (size_t)S_LEN * HIDDEN * 4;    // 32 MB
  const size_t SZ_KV = (size_t)S_LEN * 1024 * 4;     // 8 MB
  const size_t SZ_AH = (size_t)S_LEN * HIDDEN * 2;   // 16 MB
  const size_t SZ_WH = (size_t)HIDDEN * HIDDEN * 2;  // 32 MB
  const size_t needed = 2 * SZ_Q + 2 * SZ_KV + 2 * SZ_AH + 2 * SZ_WH;  // 176 MB

  // ---- MFMA-path layout (lifetimes disjoint; all within 176 MB) ----
  float* q = (float*)(ws);                         // [0, 32M)   fp32 q proj
  float* kv = (float*)(ws + 32 * MB);              // [32, 48M)  fused k|v proj (ld 2048)
  float* ao = (float*)(ws + 48 * MB);              // [48, 80M)  attn out fp32
  unsigned short* Ah = (unsigned short*)(ws + 80 * MB);   // [80, 96M)
  unsigned short* Al = (unsigned short*)(ws + 96 * MB);   // [96, 112M)
  char* whbase = ws + 112 * MB;                    // [112, 176M)
  unsigned short* Wh = (unsigned short*)(whbase);         // 32 MB (Wq / Wo)
  unsigned short* Wl = (unsigned short*)(whbase + SZ_WH); // 32 MB
  unsigned short* Wkvh = (unsigned short*)(whbase);            // 16 MB (Wk|Wv)^T hi
  unsigned short* Wkvl = (unsigned short*)(whbase + 16 * MB);  // 16 MB lo
  // attention-stage aliases (after projections, weight splits dead):
  unsigned short* Qhb = Ah;
  unsigned short* Qlb = Al;
  unsigned short* Khb = (unsigned short*)(whbase);
  unsigned short* Klb = (unsigned short*)(whbase + 4 * MB);
  unsigned short* Vth = (unsigned short*)(whbase + 8 * MB);
  unsigned short* Vtl = (unsigned short*)(whbase + 12 * MB);  // written, unused

  // ---- fallback layout ----
  float* k_fb = (float*)(ws + SZ_Q);
  float* v_fb = (float*)(ws + SZ_Q + SZ_KV);
  float* ao_fb = (float*)(ws + SZ_Q + 2 * SZ_KV);

  if (ws_size >= needed) {
    const int n4_hidden = S_LEN * HIDDEN / 4;
    split_mat<<<(n4_hidden + 255) / 256, 256, 0, stream>>>(hidden, Ah, Al, n4_hidden);

    // Q projection (N=4096)
    split_transpose<<<dim3(HIDDEN / 32, HIDDEN / 32), 256, 0, stream>>>(Wq, Wh, Wl, HIDDEN, HIDDEN, HIDDEN);
    gemm_split<<<dim3(HIDDEN / BN, S_LEN / BM), 256, 0, stream>>>(Ah, Al, Wh, Wl, q, S_LEN, HIDDEN, HIDDEN);

    // fused K|V projection (N=2048, 256 blocks = full machine)
    split_transpose<<<dim3(1024 / 32, HIDDEN / 32), 256, 0, stream>>>(Wk, Wkvh, Wkvl, HIDDEN, 1024, 1024);
    split_transpose<<<dim3(1024 / 32, HIDDEN / 32), 256, 0, stream>>>(
        Wv, Wkvh + (size_t)1024 * HIDDEN, Wkvl + (size_t)1024 * HIDDEN, HIDDEN, 1024, 1024);
    gemm_split<<<dim3(2048 / BN, S_LEN / BM), 256, 0, stream>>>(Ah, Al, Wkvh, Wkvl, kv, S_LEN, 2048, HIDDEN);

    // RoPE + bf16 split for Q/K
    {
      const int total = S_LEN * (NUM_HEADS + NUM_KV_HEADS) * 64;
      rope_convert<<<(total + 255) / 256, 256, 0, stream>>>(q, kv, 2048, pos_ids, Qhb, Qlb, Khb, Klb);
    }
    // V (cols 1024..2047 of kv) -> transposed bf16: Vt[1024][2048]
    split_transpose<<<dim3(1024 / 32, S_LEN / 32), 256, 0, stream>>>(kv + 1024, Vth, Vtl, S_LEN, 1024, 2048);

    // attention
    attn_mfma<<<dim3(32, NUM_HEADS), 256, 0, stream>>>(Qhb, Qlb, Khb, Klb, Vth, ao);

    // output projection
    split_mat<<<(n4_hidden + 255) / 256, 256, 0, stream>>>(ao, Ah, Al, n4_hidden);
    split_transpose<<<dim3(HIDDEN / 32, HIDDEN / 32), 256, 0, stream>>>(Wo, Wh, Wl, HIDDEN, HIDDEN, HIDDEN);
    gemm_split<<<dim3(HIDDEN / BN, S_LEN / BM), 256, 0, stream>>>(Ah, Al, Wh, Wl, out, S_LEN, HIDDEN, HIDDEN);
  } else {
    gemm_f32<<<dim3(HIDDEN / TN, S_LEN / TM), 256, 0, stream>>>(hidden, Wq, q, S_LEN, HIDDEN, HIDDEN);
    gemm_f32<<<dim3(1024 / TN, S_LEN / TM), 256, 0, stream>>>(hidden, Wk, k_fb, S_LEN, 1024, HIDDEN);
    gemm_f32<<<dim3(1024 / TN, S_LEN / TM), 256, 0, stream>>>(hidden, Wv, v_fb, S_LEN, 1024, HIDDEN);
    {
      const int total = S_LEN * (NUM_HEADS + NUM_KV_HEADS) * 64;
      rope_kernel<<<(total + 255) / 256, 256, 0, stream>>>(q, k_fb, pos_ids);
    }
    attn_kernel<<<dim3(S_LEN / QB, NUM_HEADS), 256, 0, stream>>>(q, k_fb, v_fb, ao_fb);
    gemm_f32<<<dim3(HIDDEN / TN, S_LEN / TM), 256, 0, stream>>>(ao_fb, Wo, out, S_LEN, HIDDEN, HIDDEN);
  }
}